// Round 9
// baseline (596.137 us; speedup 1.0000x reference)
//
#include <hip/hip_runtime.h>
#include <hip/hip_fp16.h>

#define N_NODES 100000
#define N_EDGES 1600000
#define F 64
#define NCLS 16
#define K1 8
#define BSH 11                 // bucket = row >> 11  (2048 rows)
#define NBK 49                 // ceil(100000 / 2048)
#define BROWS 2048
#define BKCAP 36864            // mean 32768 + 22 sigma
#define FSLICE 16              // fillB slice-blocks per bucket

using f16x8 = __attribute__((ext_vector_type(8))) _Float16;
using f32x4 = __attribute__((ext_vector_type(4))) float;

// ---------------- pass A: bucket edges by row-range, LDS-aggregated claiming ----------------
__global__ __launch_bounds__(256) void k_bucketA(const int* __restrict__ ei,
                                                 int* __restrict__ gcur,
                                                 int2* __restrict__ bk) {
    __shared__ int cnt[64];
    __shared__ int base[64];
    int tid = threadIdx.x;
    if (tid < 64) cnt[tid] = 0;
    __syncthreads();
    int r[4], c[4], b[4], rank[4];
    int e0 = blockIdx.x * 1024;
#pragma unroll
    for (int u = 0; u < 4; u++) {
        int e = e0 + u * 256 + tid;
        b[u] = -1;
        if (e < N_EDGES) {
            r[u] = ei[e];
            c[u] = ei[N_EDGES + e];
            if (r[u] != c[u]) {
                b[u] = r[u] >> BSH;
                rank[u] = atomicAdd(&cnt[b[u]], 1);
            }
        }
    }
    __syncthreads();
    if (tid < NBK) base[tid] = (cnt[tid] > 0) ? atomicAdd(&gcur[tid], cnt[tid]) : 0;
    __syncthreads();
#pragma unroll
    for (int u = 0; u < 4; u++)
        if (b[u] >= 0)
            bk[(size_t)b[u] * BKCAP + base[b[u]] + rank[u]] = make_int2(r[u], c[u]);
}

// ---------------- pass B1: per-bucket degree histogram ----------------
__global__ __launch_bounds__(256) void k_degB(const int2* __restrict__ bk,
                                              const int* __restrict__ gcur,
                                              int* __restrict__ deg) {
    __shared__ int hist[BROWS];
    int b = blockIdx.x;
    for (int i = threadIdx.x; i < BROWS; i += 256) hist[i] = 0;
    __syncthreads();
    int cnt = gcur[b];
    const int2* src = bk + (size_t)b * BKCAP;
    for (int i = threadIdx.x; i < cnt; i += 256)
        atomicAdd(&hist[src[i].x & (BROWS - 1)], 1);
    __syncthreads();
    int rbase = b << BSH;
    for (int i = threadIdx.x; i < BROWS; i += 256) {
        int gr = rbase + i;
        if (gr < N_NODES) deg[gr] = hist[i];
    }
}

__global__ void k_dinv(const int* __restrict__ deg, float* __restrict__ dinv) {
    int i = blockIdx.x * blockDim.x + threadIdx.x;
    if (i >= N_NODES) return;
    int d = deg[i];
    dinv[i] = d > 0 ? rsqrtf((float)d) : 0.f;
}

// ---------------- exclusive scan (rowptr) ----------------
__global__ void k_scan1(const int* __restrict__ deg, int* __restrict__ rowptr, int* __restrict__ bsum) {
    __shared__ int sd[256];
    int tid = threadIdx.x;
    int base = blockIdx.x * 1024 + tid * 4;
    int v[4];
#pragma unroll
    for (int j = 0; j < 4; j++) {
        int idx = base + j;
        v[j] = (idx < N_NODES) ? deg[idx] : 0;
    }
    int s = v[0] + v[1] + v[2] + v[3];
    sd[tid] = s;
    __syncthreads();
    for (int d = 1; d < 256; d <<= 1) {
        int t = (tid >= d) ? sd[tid - d] : 0;
        __syncthreads();
        sd[tid] += t;
        __syncthreads();
    }
    int excl = sd[tid] - s;
    if (tid == 255) bsum[blockIdx.x] = sd[255];
    int run = excl;
#pragma unroll
    for (int j = 0; j < 4; j++) {
        int idx = base + j;
        if (idx < N_NODES) rowptr[idx] = run;
        run += v[j];
    }
}

__global__ void k_scan2(int* __restrict__ bsum, int* __restrict__ rowptr, int nblk) {
    if (threadIdx.x == 0 && blockIdx.x == 0) {
        int acc = 0;
        for (int b = 0; b < nblk; b++) { int t = bsum[b]; bsum[b] = acc; acc += t; }
        rowptr[N_NODES] = acc;
    }
}

__global__ void k_scan3(int* __restrict__ rowptr, const int* __restrict__ bsum) {
    int tid = threadIdx.x;
    int base = blockIdx.x * 1024 + tid * 4;
    int off = bsum[blockIdx.x];
#pragma unroll
    for (int j = 0; j < 4; j++) {
        int idx = base + j;
        if (idx < N_NODES) rowptr[idx] += off;
    }
}

// ---------------- pass B2: bucket -> CSR, 16 slice-blocks per bucket ----------------
__global__ __launch_bounds__(256) void k_fillB(const int2* __restrict__ bk,
                                               const int* __restrict__ gcur,
                                               const int* __restrict__ rowptr,
                                               int* __restrict__ cursor,
                                               const float* __restrict__ dinv,
                                               int2* __restrict__ csr_ew) {
    int b = blockIdx.x / FSLICE;
    int s = blockIdx.x % FSLICE;
    int cnt = gcur[b];
    int per = (cnt + FSLICE - 1) / FSLICE;
    int lo = s * per;
    int hi = lo + per;
    if (hi > cnt) hi = cnt;
    const int2* src = bk + (size_t)b * BKCAP;
    for (int i = lo + threadIdx.x; i < hi; i += 256) {
        int2 rc = src[i];
        float w = -dinv[rc.x] * dinv[rc.y];
        int p = rowptr[rc.x] + atomicAdd(&cursor[rc.x], 1);
        csr_ew[p] = make_int2(rc.y, __float_as_int(w));
    }
}

// ---------------- x fp32 -> fp16, split into [K][2][N][32] half-tables ----------------
__global__ void k_cvt(const float* __restrict__ x, __half* __restrict__ T) {
    int i = blockIdx.x * blockDim.x + threadIdx.x;
    int base = i * 4;
    if (base >= N_NODES * F) return;
    int n = base >> 6;
    int c = base & 63;
    int h = c >> 5;
    int f = c & 31;
    float4 v = *(const float4*)&x[base];
    __half2 a = __floats2half2_rn(v.x, v.y);
    __half2 b = __floats2half2_rn(v.z, v.w);
    __half* out = T + ((size_t)h * N_NODES + n) * 32 + f;
    *(__half2*)out = a;
    *(__half2*)(out + 2) = b;
}

// ---------------- W1 -> fp16 B-fragment layout ----------------
__global__ void k_prepW(const float* __restrict__ W1, __half* __restrict__ Wf) {
    int t = blockIdx.x * blockDim.x + threadIdx.x;
    if (t >= K1 * 2 * 4 * 64) return;
    int lane = t & 63;
    int cb = (t >> 6) & 3;
    int fg = (t >> 8) & 1;
    int kidx = t >> 9;
    int col = cb * 16 + (lane & 15);
    int kbase = fg * 32 + (lane >> 4) * 8;
    f16x8 v;
#pragma unroll
    for (int j = 0; j < 8; j++)
        v[j] = (_Float16)W1[kidx * 4096 + (kbase + j) * 64 + col];
    *(f16x8*)(Wf + (size_t)t * 8) = v;
}

// ---------------- propagation on a 32-feature half-table ----------------
// wave = 2 nodes x 32 features. Lanes 0-31: node A (feature = lane), lanes 32-63:
// node B (feature = lane-32). Each lane also holds one edge record of its node's
// current 32-edge chunk; broadcast within the half via shfl. Row gathers are
// single 64 B lines from a 6.4 MB table. Padded slots: w=0, gather row 0.
__global__ __launch_bounds__(256) void k_prop32(const int* __restrict__ rowptr,
                                                const int2* __restrict__ csr_ew,
                                                const __half* __restrict__ src,
                                                const __half* __restrict__ prev,
                                                __half* __restrict__ dst,
                                                float alpha, float beta) {
    int wpair = (int)((blockIdx.x * blockDim.x + threadIdx.x) >> 6);
    int lane = threadIdx.x & 63;
    int nA = wpair * 2;
    if (nA >= N_NODES) return;
    int fl = lane & 31;
    int hsel = lane & 32;            // 0 = node A lanes, 32 = node B lanes
    int node = nA + (hsel ? 1 : 0);
    bool valid = node < N_NODES;
    int cb  = valid ? rowptr[node] : 0;
    int end = valid ? rowptr[node + 1] : 0;

    float acc0 = 0.f, acc1 = 0.f, acc2 = 0.f, acc3 = 0.f;

    while (true) {
        int n_own = end - cb;
        if (n_own > 32) n_own = 32;
        if (n_own < 0) n_own = 0;
        int n_oth = __shfl(n_own, lane ^ 32, 64);
        int nmax = n_own > n_oth ? n_own : n_oth;
        if (nmax == 0) break;
        int2 e = make_int2(0, 0);
        if (fl < n_own) e = csr_ew[cb + fl];
        for (int j = 0; j < nmax; j += 8) {
            int cc[8];
            float ww[8];
#pragma unroll
            for (int u = 0; u < 8; u++) {
                cc[u] = __shfl(e.x, hsel | (j + u), 64);
                ww[u] = __int_as_float(__shfl(e.y, hsel | (j + u), 64));
            }
            float vv[8];
#pragma unroll
            for (int u = 0; u < 8; u++)
                vv[u] = __half2float(src[(size_t)cc[u] * 32 + fl]);
            acc0 = fmaf(ww[0], vv[0], acc0);
            acc1 = fmaf(ww[1], vv[1], acc1);
            acc2 = fmaf(ww[2], vv[2], acc2);
            acc3 = fmaf(ww[3], vv[3], acc3);
            acc0 = fmaf(ww[4], vv[4], acc0);
            acc1 = fmaf(ww[5], vv[5], acc1);
            acc2 = fmaf(ww[6], vv[6], acc2);
            acc3 = fmaf(ww[7], vv[7], acc3);
        }
        cb += n_own;
    }

    if (!valid) return;
    float res = alpha * ((acc0 + acc1) + (acc2 + acc3));
    if (beta != 0.f) res -= beta * __half2float(prev[(size_t)node * 32 + fl]);
    dst[(size_t)node * 32 + fl] = __float2half(res);
}

// ---------------- fused MFMA: y = softmax(relu(sum_k Tk@W1k + b1) @ W2 + b2) ----------------
// T layout: [K1][2][N][32]; fragment (kidx,fg) reads half fg.
__global__ __launch_bounds__(256) void k_fused_mfma(const __half* __restrict__ T,
                                                    const __half* __restrict__ Wf,
                                                    const float* __restrict__ b1,
                                                    const float* __restrict__ W2,
                                                    const float* __restrict__ b2,
                                                    float* __restrict__ y) {
    __shared__ float Ht[64][65];
    __shared__ float W2l[64 * 16];
    __shared__ float b2l[16];
    int tid = threadIdx.x;
    int lane = tid & 63;
    int w = tid >> 6;
    int ln15 = lane & 15;
    int lg = lane >> 4;
    int base = blockIdx.x * 64;

    for (int j = tid; j < 64 * 16; j += 256) W2l[j] = W2[j];
    if (tid < 16) b2l[tid] = b2[tid];

    int nd = base + (w << 4) + ln15;
    if (nd > N_NODES - 1) nd = N_NODES - 1;  // clamp: garbage rows, stores guarded

    f32x4 acc0 = {0.f, 0.f, 0.f, 0.f};
    f32x4 acc1 = {0.f, 0.f, 0.f, 0.f};
    f32x4 acc2 = {0.f, 0.f, 0.f, 0.f};
    f32x4 acc3 = {0.f, 0.f, 0.f, 0.f};

    for (int s = 0; s < 16; s++) {
        int kidx = s >> 1;
        int fg = s & 1;
        f16x8 a = *(const f16x8*)(T + ((size_t)(kidx * 2 + fg) * N_NODES + nd) * 32 + lg * 8);
        const __half* wb = Wf + ((size_t)((kidx * 2 + fg) * 4) * 64 + lane) * 8;
        f16x8 b0 = *(const f16x8*)(wb);
        f16x8 b1f = *(const f16x8*)(wb + 64 * 8);
        f16x8 b2f = *(const f16x8*)(wb + 128 * 8);
        f16x8 b3f = *(const f16x8*)(wb + 192 * 8);
        acc0 = __builtin_amdgcn_mfma_f32_16x16x32_f16(a, b0, acc0, 0, 0, 0);
        acc1 = __builtin_amdgcn_mfma_f32_16x16x32_f16(a, b1f, acc1, 0, 0, 0);
        acc2 = __builtin_amdgcn_mfma_f32_16x16x32_f16(a, b2f, acc2, 0, 0, 0);
        acc3 = __builtin_amdgcn_mfma_f32_16x16x32_f16(a, b3f, acc3, 0, 0, 0);
    }

    int hrow = (w << 4) + (lg << 2);
    {
        float bb0 = b1[0 * 16 + ln15];
        float bb1 = b1[1 * 16 + ln15];
        float bb2 = b1[2 * 16 + ln15];
        float bb3 = b1[3 * 16 + ln15];
#pragma unroll
        for (int r = 0; r < 4; r++) {
            float h0 = acc0[r] + bb0;
            float h1 = acc1[r] + bb1;
            float h2 = acc2[r] + bb2;
            float h3 = acc3[r] + bb3;
            Ht[hrow + r][0 * 16 + ln15] = h0 > 0.f ? h0 : 0.f;
            Ht[hrow + r][1 * 16 + ln15] = h1 > 0.f ? h1 : 0.f;
            Ht[hrow + r][2 * 16 + ln15] = h2 > 0.f ? h2 : 0.f;
            Ht[hrow + r][3 * 16 + ln15] = h3 > 0.f ? h3 : 0.f;
        }
    }
    __syncthreads();

    int node = tid >> 2;
    int cg = tid & 3;
    int gnode = base + node;
    if (gnode >= N_NODES) return;
    float l0 = b2l[cg * 4 + 0], l1 = b2l[cg * 4 + 1], l2 = b2l[cg * 4 + 2], l3 = b2l[cg * 4 + 3];
    for (int f = 0; f < 64; f++) {
        float h = Ht[node][f];
        l0 = fmaf(h, W2l[f * 16 + cg * 4 + 0], l0);
        l1 = fmaf(h, W2l[f * 16 + cg * 4 + 1], l1);
        l2 = fmaf(h, W2l[f * 16 + cg * 4 + 2], l2);
        l3 = fmaf(h, W2l[f * 16 + cg * 4 + 3], l3);
    }
    float m = fmaxf(fmaxf(l0, l1), fmaxf(l2, l3));
    m = fmaxf(m, __shfl_xor(m, 1, 64));
    m = fmaxf(m, __shfl_xor(m, 2, 64));
    float e0 = expf(l0 - m), e1 = expf(l1 - m), e2 = expf(l2 - m), e3 = expf(l3 - m);
    float s = e0 + e1 + e2 + e3;
    s += __shfl_xor(s, 1, 64);
    s += __shfl_xor(s, 2, 64);
    float inv = 1.f / s;
    float4 o = make_float4(e0 * inv, e1 * inv, e2 * inv, e3 * inv);
    *(float4*)&y[(size_t)gnode * 16 + cg * 4] = o;
}

// ---------------- launch ----------------

extern "C" void kernel_launch(void* const* d_in, const int* in_sizes, int n_in,
                              void* d_out, int out_size, void* d_ws, size_t ws_size,
                              hipStream_t stream) {
    const float* x  = (const float*)d_in[0];
    const int*   ei = (const int*)d_in[1];
    const float* W1 = (const float*)d_in[2];
    const float* b1 = (const float*)d_in[3];
    const float* W2 = (const float*)d_in[4];
    const float* b2 = (const float*)d_in[5];
    float* y = (float*)d_out;

    char* p = (char*)d_ws;
    auto alloc = [&](size_t bytes) {
        char* q = p;
        p += (bytes + 255) & ~(size_t)255;
        return q;
    };
    int*   deg    = (int*)alloc((size_t)N_NODES * 4);
    float* dinv   = (float*)alloc((size_t)N_NODES * 4);
    int*   rowptr = (int*)alloc((size_t)(N_NODES + 1) * 4);
    int*   bsum   = (int*)alloc(128 * 4);
    int*   gcur   = (int*)alloc(64 * 4);
    int*   cursor = (int*)alloc((size_t)N_NODES * 4);
    int2*  csr_ew = (int2*)alloc((size_t)N_EDGES * 8);
    __half* T     = (__half*)alloc((size_t)K1 * 2 * N_NODES * 32 * 2);
    __half* Wf    = (__half*)alloc((size_t)K1 * 2 * 4 * 64 * 8 * 2);

    // bucket buffer (14.5 MB) aliases T: dead before k_cvt/k_prop write T.
    int2* bk = (int2*)T;

    hipMemsetAsync(gcur, 0, 64 * 4, stream);
    hipMemsetAsync(cursor, 0, (size_t)N_NODES * 4, stream);

    int nb = (N_NODES + 255) / 256;
    k_bucketA<<<(N_EDGES + 1023) / 1024, 256, 0, stream>>>(ei, gcur, bk);
    k_degB<<<NBK, 256, 0, stream>>>(bk, gcur, deg);
    k_dinv<<<nb, 256, 0, stream>>>(deg, dinv);
    int nblk = (N_NODES + 1023) / 1024;
    k_scan1<<<nblk, 256, 0, stream>>>(deg, rowptr, bsum);
    k_scan2<<<1, 64, 0, stream>>>(bsum, rowptr, nblk);
    k_scan3<<<nblk, 256, 0, stream>>>(rowptr, bsum);
    k_fillB<<<NBK * FSLICE, 256, 0, stream>>>(bk, gcur, rowptr, cursor, dinv, csr_ew);
    k_prepW<<<16, 256, 0, stream>>>(W1, Wf);

    auto Tkh = [&](int k, int h) {
        return T + ((size_t)(k * 2 + h) * N_NODES) * 32;
    };

    k_cvt<<<(N_NODES * F / 4 + 255) / 256, 256, 0, stream>>>(x, Tkh(0, 0));

    int npair = (N_NODES + 1) / 2;
    int prop_blocks = (npair + 3) / 4;
    for (int h = 0; h < 2; h++)
        k_prop32<<<prop_blocks, 256, 0, stream>>>(rowptr, csr_ew, Tkh(0, h), Tkh(0, h), Tkh(1, h), 1.f, 0.f);
    for (int k = 2; k < K1; k++)
        for (int h = 0; h < 2; h++)
            k_prop32<<<prop_blocks, 256, 0, stream>>>(rowptr, csr_ew, Tkh(k - 1, h), Tkh(k - 2, h), Tkh(k, h), 2.f, 1.f);

    int gemm_blocks = (N_NODES + 63) / 64;
    k_fused_mfma<<<gemm_blocks, 256, 0, stream>>>(T, Wf, b1, W2, b2, y);
}

// Round 10
// 464.440 us; speedup vs baseline: 1.2836x; 1.2836x over previous
//
#include <hip/hip_runtime.h>
#include <hip/hip_fp16.h>

#define N_NODES 100000
#define N_EDGES 1600000
#define F 64
#define NCLS 16
#define K1 8
#define BSH 9                  // bucket = row >> 9  (512 rows)
#define NBK 196                // ceil(100000 / 512)
#define BROWS 512
#define BKCAP 9216             // mean 8192 + ~11 sigma

using f16x8 = __attribute__((ext_vector_type(8))) _Float16;
using f32x4 = __attribute__((ext_vector_type(4))) float;

// ---------------- pass A: bucket edges by row-range, LDS-aggregated claiming ----------------
// 1024 edges/block; one global atomic per (block,bucket); ~contiguous chunk writes.
__global__ __launch_bounds__(256) void k_bucketA(const int* __restrict__ ei,
                                                 int* __restrict__ gcur,
                                                 int2* __restrict__ bk) {
    __shared__ int cnt[256];
    __shared__ int base[256];
    int tid = threadIdx.x;
    cnt[tid] = 0;
    __syncthreads();
    int r[4], c[4], b[4], rank[4];
    int e0 = blockIdx.x * 1024;
#pragma unroll
    for (int u = 0; u < 4; u++) {
        int e = e0 + u * 256 + tid;
        b[u] = -1;
        if (e < N_EDGES) {
            r[u] = ei[e];
            c[u] = ei[N_EDGES + e];
            if (r[u] != c[u]) {
                b[u] = r[u] >> BSH;
                rank[u] = atomicAdd(&cnt[b[u]], 1);
            }
        }
    }
    __syncthreads();
    if (tid < NBK) base[tid] = (cnt[tid] > 0) ? atomicAdd(&gcur[tid], cnt[tid]) : 0;
    __syncthreads();
#pragma unroll
    for (int u = 0; u < 4; u++)
        if (b[u] >= 0)
            bk[(size_t)b[u] * BKCAP + base[b[u]] + rank[u]] = make_int2(r[u], c[u]);
}

// ---------------- pass B1: per-bucket degree histogram (no global atomics) ----------------
__global__ __launch_bounds__(256) void k_degB(const int2* __restrict__ bk,
                                              const int* __restrict__ gcur,
                                              int* __restrict__ deg) {
    __shared__ int hist[BROWS];
    int b = blockIdx.x;
    for (int i = threadIdx.x; i < BROWS; i += 256) hist[i] = 0;
    __syncthreads();
    int cnt = gcur[b];
    const int2* src = bk + (size_t)b * BKCAP;
    for (int i = threadIdx.x; i < cnt; i += 256)
        atomicAdd(&hist[src[i].x & (BROWS - 1)], 1);
    __syncthreads();
    int rbase = b << BSH;
    for (int i = threadIdx.x; i < BROWS; i += 256) {
        int gr = rbase + i;
        if (gr < N_NODES) deg[gr] = hist[i];
    }
}

__global__ void k_dinv(const int* __restrict__ deg, float* __restrict__ dinv) {
    int i = blockIdx.x * blockDim.x + threadIdx.x;
    if (i >= N_NODES) return;
    int d = deg[i];
    dinv[i] = d > 0 ? rsqrtf((float)d) : 0.f;
}

// ---------------- exclusive scan (rowptr) ----------------
__global__ void k_scan1(const int* __restrict__ deg, int* __restrict__ rowptr, int* __restrict__ bsum) {
    __shared__ int sd[256];
    int tid = threadIdx.x;
    int base = blockIdx.x * 1024 + tid * 4;
    int v[4];
#pragma unroll
    for (int j = 0; j < 4; j++) {
        int idx = base + j;
        v[j] = (idx < N_NODES) ? deg[idx] : 0;
    }
    int s = v[0] + v[1] + v[2] + v[3];
    sd[tid] = s;
    __syncthreads();
    for (int d = 1; d < 256; d <<= 1) {
        int t = (tid >= d) ? sd[tid - d] : 0;
        __syncthreads();
        sd[tid] += t;
        __syncthreads();
    }
    int excl = sd[tid] - s;
    if (tid == 255) bsum[blockIdx.x] = sd[255];
    int run = excl;
#pragma unroll
    for (int j = 0; j < 4; j++) {
        int idx = base + j;
        if (idx < N_NODES) rowptr[idx] = run;
        run += v[j];
    }
}

__global__ void k_scan2(int* __restrict__ bsum, int* __restrict__ rowptr, int nblk) {
    if (threadIdx.x == 0 && blockIdx.x == 0) {
        int acc = 0;
        for (int b = 0; b < nblk; b++) { int t = bsum[b]; bsum[b] = acc; acc += t; }
        rowptr[N_NODES] = acc;
    }
}

__global__ void k_scan3(int* __restrict__ rowptr, const int* __restrict__ bsum) {
    int tid = threadIdx.x;
    int base = blockIdx.x * 1024 + tid * 4;
    int off = bsum[blockIdx.x];
#pragma unroll
    for (int j = 0; j < 4; j++) {
        int idx = base + j;
        if (idx < N_NODES) rowptr[idx] += off;
    }
}

// ---------------- pass B2: bucket -> CSR, one block per bucket, LDS row-cursors ----------------
// 196 blocks; write window 64KB/block, ~25 windows/XCD -> fits L2 -> write-amp ~1.
__global__ __launch_bounds__(256) void k_fillB(const int2* __restrict__ bk,
                                               const int* __restrict__ gcur,
                                               const int* __restrict__ rowptr,
                                               const float* __restrict__ dinv,
                                               int2* __restrict__ csr_ew) {
    __shared__ int cur[BROWS];
    int b = blockIdx.x;
    for (int i = threadIdx.x; i < BROWS; i += 256) cur[i] = 0;
    __syncthreads();
    int cnt = gcur[b];
    const int2* src = bk + (size_t)b * BKCAP;
    for (int i = threadIdx.x; i < cnt; i += 256) {
        int2 rc = src[i];
        int rank = atomicAdd(&cur[rc.x & (BROWS - 1)], 1);
        float w = -dinv[rc.x] * dinv[rc.y];
        csr_ew[rowptr[rc.x] + rank] = make_int2(rc.y, __float_as_int(w));
    }
}

// ---------------- x fp32 -> fp16 ----------------
__global__ void k_cvt(const float* __restrict__ x, __half* __restrict__ t0) {
    int i = blockIdx.x * blockDim.x + threadIdx.x;
    int base = i * 4;
    if (base >= N_NODES * F) return;
    float4 v = *(const float4*)&x[base];
    __half2 a = __floats2half2_rn(v.x, v.y);
    __half2 b = __floats2half2_rn(v.z, v.w);
    *(__half2*)&t0[base] = a;
    *(__half2*)&t0[base + 2] = b;
}

// ---------------- W1 -> fp16 B-fragment layout ----------------
__global__ void k_prepW(const float* __restrict__ W1, __half* __restrict__ Wf) {
    int t = blockIdx.x * blockDim.x + threadIdx.x;
    if (t >= K1 * 2 * 4 * 64) return;
    int lane = t & 63;
    int cb = (t >> 6) & 3;
    int fg = (t >> 8) & 1;
    int kidx = t >> 9;
    int col = cb * 16 + (lane & 15);
    int kbase = fg * 32 + (lane >> 4) * 8;
    f16x8 v;
#pragma unroll
    for (int j = 0; j < 8; j++)
        v[j] = (_Float16)W1[kidx * 4096 + (kbase + j) * 64 + col];
    *(f16x8*)(Wf + (size_t)t * 8) = v;
}

// ---------------- propagation (round-4 version): dst = alpha*(L_hat@src) - beta*prev ----------------
__global__ __launch_bounds__(256) void k_prop(const int* __restrict__ rowptr,
                                              const int2* __restrict__ csr_ew,
                                              const __half* __restrict__ src,
                                              const __half* __restrict__ prev,
                                              __half* __restrict__ dst,
                                              float alpha, float beta) {
    int wid = (int)((blockIdx.x * blockDim.x + threadIdx.x) >> 6);
    int lane = threadIdx.x & 63;
    if (wid >= N_NODES) return;
    int beg = rowptr[wid], end = rowptr[wid + 1];

    float acc0 = 0.f, acc1 = 0.f, acc2 = 0.f, acc3 = 0.f;

    for (int cb = beg; cb < end; cb += 64) {
        int n = end - cb;
        if (n > 64) n = 64;
        int2 e = make_int2(0, 0);
        if (lane < n) e = csr_ew[cb + lane];

        int j = 0;
        for (; j + 7 < n; j += 8) {
            int cc[8];
            float ww[8];
#pragma unroll
            for (int u = 0; u < 8; u++) {
                cc[u] = __shfl(e.x, j + u, 64);
                ww[u] = __int_as_float(__shfl(e.y, j + u, 64));
            }
            float vv[8];
#pragma unroll
            for (int u = 0; u < 8; u++)
                vv[u] = __half2float(src[(size_t)cc[u] * F + lane]);
            acc0 = fmaf(ww[0], vv[0], acc0);
            acc1 = fmaf(ww[1], vv[1], acc1);
            acc2 = fmaf(ww[2], vv[2], acc2);
            acc3 = fmaf(ww[3], vv[3], acc3);
            acc0 = fmaf(ww[4], vv[4], acc0);
            acc1 = fmaf(ww[5], vv[5], acc1);
            acc2 = fmaf(ww[6], vv[6], acc2);
            acc3 = fmaf(ww[7], vv[7], acc3);
        }
        for (; j + 3 < n; j += 4) {
            int cc[4];
            float ww[4];
#pragma unroll
            for (int u = 0; u < 4; u++) {
                cc[u] = __shfl(e.x, j + u, 64);
                ww[u] = __int_as_float(__shfl(e.y, j + u, 64));
            }
            float vv[4];
#pragma unroll
            for (int u = 0; u < 4; u++)
                vv[u] = __half2float(src[(size_t)cc[u] * F + lane]);
            acc0 = fmaf(ww[0], vv[0], acc0);
            acc1 = fmaf(ww[1], vv[1], acc1);
            acc2 = fmaf(ww[2], vv[2], acc2);
            acc3 = fmaf(ww[3], vv[3], acc3);
        }
        for (; j < n; j++) {
            int c0 = __shfl(e.x, j, 64);
            float w0 = __int_as_float(__shfl(e.y, j, 64));
            acc0 = fmaf(w0, __half2float(src[(size_t)c0 * F + lane]), acc0);
        }
    }

    float res = alpha * ((acc0 + acc1) + (acc2 + acc3));
    if (beta != 0.f) res -= beta * __half2float(prev[(size_t)wid * F + lane]);
    dst[(size_t)wid * F + lane] = __float2half(res);
}

// ---------------- fused MFMA: y = softmax(relu(sum_k Tk@W1k + b1) @ W2 + b2) ----------------
__global__ __launch_bounds__(256) void k_fused_mfma(const __half* __restrict__ T,
                                                    const __half* __restrict__ Wf,
                                                    const float* __restrict__ b1,
                                                    const float* __restrict__ W2,
                                                    const float* __restrict__ b2,
                                                    float* __restrict__ y) {
    __shared__ float Ht[64][65];
    __shared__ float W2l[64 * 16];
    __shared__ float b2l[16];
    int tid = threadIdx.x;
    int lane = tid & 63;
    int w = tid >> 6;
    int ln15 = lane & 15;
    int lg = lane >> 4;
    int base = blockIdx.x * 64;

    for (int j = tid; j < 64 * 16; j += 256) W2l[j] = W2[j];
    if (tid < 16) b2l[tid] = b2[tid];

    int nd = base + (w << 4) + ln15;
    if (nd > N_NODES - 1) nd = N_NODES - 1;  // clamp: garbage rows, stores guarded

    f32x4 acc0 = {0.f, 0.f, 0.f, 0.f};
    f32x4 acc1 = {0.f, 0.f, 0.f, 0.f};
    f32x4 acc2 = {0.f, 0.f, 0.f, 0.f};
    f32x4 acc3 = {0.f, 0.f, 0.f, 0.f};

    for (int s = 0; s < 16; s++) {
        int kidx = s >> 1;
        int fg = s & 1;
        f16x8 a = *(const f16x8*)(T + ((size_t)kidx * N_NODES + nd) * F + fg * 32 + lg * 8);
        const __half* wb = Wf + ((size_t)((kidx * 2 + fg) * 4) * 64 + lane) * 8;
        f16x8 b0 = *(const f16x8*)(wb);
        f16x8 b1f = *(const f16x8*)(wb + 64 * 8);
        f16x8 b2f = *(const f16x8*)(wb + 128 * 8);
        f16x8 b3f = *(const f16x8*)(wb + 192 * 8);
        acc0 = __builtin_amdgcn_mfma_f32_16x16x32_f16(a, b0, acc0, 0, 0, 0);
        acc1 = __builtin_amdgcn_mfma_f32_16x16x32_f16(a, b1f, acc1, 0, 0, 0);
        acc2 = __builtin_amdgcn_mfma_f32_16x16x32_f16(a, b2f, acc2, 0, 0, 0);
        acc3 = __builtin_amdgcn_mfma_f32_16x16x32_f16(a, b3f, acc3, 0, 0, 0);
    }

    int hrow = (w << 4) + (lg << 2);
    {
        float bb0 = b1[0 * 16 + ln15];
        float bb1 = b1[1 * 16 + ln15];
        float bb2 = b1[2 * 16 + ln15];
        float bb3 = b1[3 * 16 + ln15];
#pragma unroll
        for (int r = 0; r < 4; r++) {
            float h0 = acc0[r] + bb0;
            float h1 = acc1[r] + bb1;
            float h2 = acc2[r] + bb2;
            float h3 = acc3[r] + bb3;
            Ht[hrow + r][0 * 16 + ln15] = h0 > 0.f ? h0 : 0.f;
            Ht[hrow + r][1 * 16 + ln15] = h1 > 0.f ? h1 : 0.f;
            Ht[hrow + r][2 * 16 + ln15] = h2 > 0.f ? h2 : 0.f;
            Ht[hrow + r][3 * 16 + ln15] = h3 > 0.f ? h3 : 0.f;
        }
    }
    __syncthreads();

    int node = tid >> 2;
    int cg = tid & 3;
    int gnode = base + node;
    if (gnode >= N_NODES) return;
    float l0 = b2l[cg * 4 + 0], l1 = b2l[cg * 4 + 1], l2 = b2l[cg * 4 + 2], l3 = b2l[cg * 4 + 3];
    for (int f = 0; f < 64; f++) {
        float h = Ht[node][f];
        l0 = fmaf(h, W2l[f * 16 + cg * 4 + 0], l0);
        l1 = fmaf(h, W2l[f * 16 + cg * 4 + 1], l1);
        l2 = fmaf(h, W2l[f * 16 + cg * 4 + 2], l2);
        l3 = fmaf(h, W2l[f * 16 + cg * 4 + 3], l3);
    }
    float m = fmaxf(fmaxf(l0, l1), fmaxf(l2, l3));
    m = fmaxf(m, __shfl_xor(m, 1, 64));
    m = fmaxf(m, __shfl_xor(m, 2, 64));
    float e0 = expf(l0 - m), e1 = expf(l1 - m), e2 = expf(l2 - m), e3 = expf(l3 - m);
    float s = e0 + e1 + e2 + e3;
    s += __shfl_xor(s, 1, 64);
    s += __shfl_xor(s, 2, 64);
    float inv = 1.f / s;
    float4 o = make_float4(e0 * inv, e1 * inv, e2 * inv, e3 * inv);
    *(float4*)&y[(size_t)gnode * 16 + cg * 4] = o;
}

// ---------------- launch ----------------

extern "C" void kernel_launch(void* const* d_in, const int* in_sizes, int n_in,
                              void* d_out, int out_size, void* d_ws, size_t ws_size,
                              hipStream_t stream) {
    const float* x  = (const float*)d_in[0];
    const int*   ei = (const int*)d_in[1];
    const float* W1 = (const float*)d_in[2];
    const float* b1 = (const float*)d_in[3];
    const float* W2 = (const float*)d_in[4];
    const float* b2 = (const float*)d_in[5];
    float* y = (float*)d_out;

    char* p = (char*)d_ws;
    auto alloc = [&](size_t bytes) {
        char* q = p;
        p += (bytes + 255) & ~(size_t)255;
        return q;
    };
    int*   deg    = (int*)alloc((size_t)N_NODES * 4);
    float* dinv   = (float*)alloc((size_t)N_NODES * 4);
    int*   rowptr = (int*)alloc((size_t)(N_NODES + 1) * 4);
    int*   bsum   = (int*)alloc(128 * 4);
    int*   gcur   = (int*)alloc(256 * 4);
    int2*  csr_ew = (int2*)alloc((size_t)N_EDGES * 8);
    __half* T     = (__half*)alloc((size_t)K1 * N_NODES * F * 2);
    __half* Wf    = (__half*)alloc((size_t)K1 * 2 * 4 * 64 * 8 * 2);

    // bucket buffer (196*9216*8B = 14.5 MB) aliases T: dead before k_cvt/k_prop write T.
    int2* bk = (int2*)T;

    hipMemsetAsync(gcur, 0, 256 * 4, stream);

    int nb = (N_NODES + 255) / 256;
    k_bucketA<<<(N_EDGES + 1023) / 1024, 256, 0, stream>>>(ei, gcur, bk);
    k_degB<<<NBK, 256, 0, stream>>>(bk, gcur, deg);
    k_dinv<<<nb, 256, 0, stream>>>(deg, dinv);
    int nblk = (N_NODES + 1023) / 1024;
    k_scan1<<<nblk, 256, 0, stream>>>(deg, rowptr, bsum);
    k_scan2<<<1, 64, 0, stream>>>(bsum, rowptr, nblk);
    k_scan3<<<nblk, 256, 0, stream>>>(rowptr, bsum);
    k_fillB<<<NBK, 256, 0, stream>>>(bk, gcur, rowptr, dinv, csr_ew);
    k_prepW<<<16, 256, 0, stream>>>(W1, Wf);

    const size_t TSZ = (size_t)N_NODES * F;
    __half* Tk[K1];
    for (int k = 0; k < K1; k++) Tk[k] = T + (size_t)k * TSZ;

    k_cvt<<<(N_NODES * F / 4 + 255) / 256, 256, 0, stream>>>(x, Tk[0]);

    int prop_blocks = (N_NODES + 3) / 4;
    k_prop<<<prop_blocks, 256, 0, stream>>>(rowptr, csr_ew, Tk[0], Tk[0], Tk[1], 1.f, 0.f);
    for (int k = 2; k < K1; k++)
        k_prop<<<prop_blocks, 256, 0, stream>>>(rowptr, csr_ew, Tk[k - 1], Tk[k - 2], Tk[k], 2.f, 1.f);

    int gemm_blocks = (N_NODES + 63) / 64;
    k_fused_mfma<<<gemm_blocks, 256, 0, stream>>>(T, Wf, b1, W2, b2, y);
}

// Round 11
// 405.934 us; speedup vs baseline: 1.4686x; 1.1441x over previous
//
#include <hip/hip_runtime.h>
#include <hip/hip_fp16.h>

#define N_NODES 100000
#define N_EDGES 1600000
#define F 64
#define NCLS 16
#define K1 8
#define BSH 9                  // bucket = row >> 9  (512 rows)
#define NBK 196                // ceil(100000 / 512)
#define BROWS 512
#define BKCAP 9216             // mean 8192 + ~11 sigma

using f16x8 = __attribute__((ext_vector_type(8))) _Float16;
using f32x4 = __attribute__((ext_vector_type(4))) float;

// ---------------- pass A: bucket edges by row-range, LDS-aggregated claiming ----------------
__global__ __launch_bounds__(256) void k_bucketA(const int* __restrict__ ei,
                                                 int* __restrict__ gcur,
                                                 int2* __restrict__ bk) {
    __shared__ int cnt[256];
    __shared__ int base[256];
    int tid = threadIdx.x;
    cnt[tid] = 0;
    __syncthreads();
    int r[4], c[4], b[4], rank[4];
    int e0 = blockIdx.x * 1024;
#pragma unroll
    for (int u = 0; u < 4; u++) {
        int e = e0 + u * 256 + tid;
        b[u] = -1;
        if (e < N_EDGES) {
            r[u] = ei[e];
            c[u] = ei[N_EDGES + e];
            if (r[u] != c[u]) {
                b[u] = r[u] >> BSH;
                rank[u] = atomicAdd(&cnt[b[u]], 1);
            }
        }
    }
    __syncthreads();
    if (tid < NBK) base[tid] = (cnt[tid] > 0) ? atomicAdd(&gcur[tid], cnt[tid]) : 0;
    __syncthreads();
#pragma unroll
    for (int u = 0; u < 4; u++)
        if (b[u] >= 0)
            bk[(size_t)b[u] * BKCAP + base[b[u]] + rank[u]] = make_int2(r[u], c[u]);
}

// ---------------- pass B1: per-bucket degree histogram + dinv (fused) ----------------
__global__ __launch_bounds__(256) void k_degB(const int2* __restrict__ bk,
                                              const int* __restrict__ gcur,
                                              int* __restrict__ deg,
                                              float* __restrict__ dinv) {
    __shared__ int hist[BROWS];
    int b = blockIdx.x;
    for (int i = threadIdx.x; i < BROWS; i += 256) hist[i] = 0;
    __syncthreads();
    int cnt = gcur[b];
    const int2* src = bk + (size_t)b * BKCAP;
    for (int i = threadIdx.x; i < cnt; i += 256)
        atomicAdd(&hist[src[i].x & (BROWS - 1)], 1);
    __syncthreads();
    int rbase = b << BSH;
    for (int i = threadIdx.x; i < BROWS; i += 256) {
        int gr = rbase + i;
        if (gr < N_NODES) {
            int d = hist[i];
            deg[gr] = d;
            dinv[gr] = d > 0 ? rsqrtf((float)d) : 0.f;
        }
    }
}

// ---------------- exclusive scan (rowptr) ----------------
__global__ void k_scan1(const int* __restrict__ deg, int* __restrict__ rowptr, int* __restrict__ bsum) {
    __shared__ int sd[256];
    int tid = threadIdx.x;
    int base = blockIdx.x * 1024 + tid * 4;
    int v[4];
#pragma unroll
    for (int j = 0; j < 4; j++) {
        int idx = base + j;
        v[j] = (idx < N_NODES) ? deg[idx] : 0;
    }
    int s = v[0] + v[1] + v[2] + v[3];
    sd[tid] = s;
    __syncthreads();
    for (int d = 1; d < 256; d <<= 1) {
        int t = (tid >= d) ? sd[tid - d] : 0;
        __syncthreads();
        sd[tid] += t;
        __syncthreads();
    }
    int excl = sd[tid] - s;
    if (tid == 255) bsum[blockIdx.x] = sd[255];
    int run = excl;
#pragma unroll
    for (int j = 0; j < 4; j++) {
        int idx = base + j;
        if (idx < N_NODES) rowptr[idx] = run;
        run += v[j];
    }
}

__global__ void k_scan2(int* __restrict__ bsum, int* __restrict__ rowptr, int nblk) {
    if (threadIdx.x == 0 && blockIdx.x == 0) {
        int acc = 0;
        for (int b = 0; b < nblk; b++) { int t = bsum[b]; bsum[b] = acc; acc += t; }
        rowptr[N_NODES] = acc;
    }
}

__global__ void k_scan3(int* __restrict__ rowptr, const int* __restrict__ bsum) {
    int tid = threadIdx.x;
    int base = blockIdx.x * 1024 + tid * 4;
    int off = bsum[blockIdx.x];
#pragma unroll
    for (int j = 0; j < 4; j++) {
        int idx = base + j;
        if (idx < N_NODES) rowptr[idx] += off;
    }
}

// ---------------- pass B2: bucket -> CSR, one block per bucket, LDS row-cursors ----------------
__global__ __launch_bounds__(256) void k_fillB(const int2* __restrict__ bk,
                                               const int* __restrict__ gcur,
                                               const int* __restrict__ rowptr,
                                               const float* __restrict__ dinv,
                                               int2* __restrict__ csr_ew) {
    __shared__ int cur[BROWS];
    int b = blockIdx.x;
    for (int i = threadIdx.x; i < BROWS; i += 256) cur[i] = 0;
    __syncthreads();
    int cnt = gcur[b];
    const int2* src = bk + (size_t)b * BKCAP;
    for (int i = threadIdx.x; i < cnt; i += 256) {
        int2 rc = src[i];
        int rank = atomicAdd(&cur[rc.x & (BROWS - 1)], 1);
        float w = -dinv[rc.x] * dinv[rc.y];
        csr_ew[rowptr[rc.x] + rank] = make_int2(rc.y, __float_as_int(w));
    }
}

// ---------------- x fp32 -> fp16 ----------------
__global__ void k_cvt(const float* __restrict__ x, __half* __restrict__ t0) {
    int i = blockIdx.x * blockDim.x + threadIdx.x;
    int base = i * 4;
    if (base >= N_NODES * F) return;
    float4 v = *(const float4*)&x[base];
    __half2 a = __floats2half2_rn(v.x, v.y);
    __half2 b = __floats2half2_rn(v.z, v.w);
    *(__half2*)&t0[base] = a;
    *(__half2*)&t0[base + 2] = b;
}

// ---------------- W1 -> fp16 B-fragment layout ----------------
__global__ void k_prepW(const float* __restrict__ W1, __half* __restrict__ Wf) {
    int t = blockIdx.x * blockDim.x + threadIdx.x;
    if (t >= K1 * 2 * 4 * 64) return;
    int lane = t & 63;
    int cb = (t >> 6) & 3;
    int fg = (t >> 8) & 1;
    int kidx = t >> 9;
    int col = cb * 16 + (lane & 15);
    int kbase = fg * 32 + (lane >> 4) * 8;
    f16x8 v;
#pragma unroll
    for (int j = 0; j < 8; j++)
        v[j] = (_Float16)W1[kidx * 4096 + (kbase + j) * 64 + col];
    *(f16x8*)(Wf + (size_t)t * 8) = v;
}

// ---------------- propagation: wide-gather version ----------------
// one wave per node. 16 lanes cover one row (8 B = 4 fp16 each); wave processes
// 4 edges per load instruction (4 rows x 128 B). lane quarter q = lane>>4 owns
// edge j+g*4+q; per-quarter partial accumulators folded by shfl_xor(16|32) at end.
__global__ __launch_bounds__(256) void k_prop(const int* __restrict__ rowptr,
                                              const int2* __restrict__ csr_ew,
                                              const __half* __restrict__ src,
                                              const __half* __restrict__ prev,
                                              __half* __restrict__ dst,
                                              float alpha, float beta) {
    int wid = (int)((blockIdx.x * blockDim.x + threadIdx.x) >> 6);
    int lane = threadIdx.x & 63;
    if (wid >= N_NODES) return;
    int beg = rowptr[wid], end = rowptr[wid + 1];
    int q = lane >> 4;          // edge-quarter
    int fb = (lane & 15) * 4;   // feature base (4 fp16)

    float acc0 = 0.f, acc1 = 0.f, acc2 = 0.f, acc3 = 0.f;

    for (int cb = beg; cb < end; cb += 64) {
        int n = end - cb;
        if (n > 64) n = 64;
        int2 e = make_int2(0, 0);
        if (lane < n) e = csr_ew[cb + lane];
        for (int j = 0; j < n; j += 16) {
            int cc[4];
            float ww[4];
#pragma unroll
            for (int g = 0; g < 4; g++) {
                int sl = j + g * 4 + q;
                cc[g] = __shfl(e.x, sl, 64);
                ww[g] = __int_as_float(__shfl(e.y, sl, 64));
            }
            uint2 raw[4];
#pragma unroll
            for (int g = 0; g < 4; g++)
                raw[g] = *(const uint2*)(src + (size_t)cc[g] * F + fb);
#pragma unroll
            for (int g = 0; g < 4; g++) {
                float2 lo = __half22float2(*(__half2*)&raw[g].x);
                float2 hi = __half22float2(*(__half2*)&raw[g].y);
                acc0 = fmaf(ww[g], lo.x, acc0);
                acc1 = fmaf(ww[g], lo.y, acc1);
                acc2 = fmaf(ww[g], hi.x, acc2);
                acc3 = fmaf(ww[g], hi.y, acc3);
            }
        }
    }

    // fold the 4 edge-quarters (feature group l&15 invariant under xor 16/32)
    acc0 += __shfl_xor(acc0, 16, 64); acc0 += __shfl_xor(acc0, 32, 64);
    acc1 += __shfl_xor(acc1, 16, 64); acc1 += __shfl_xor(acc1, 32, 64);
    acc2 += __shfl_xor(acc2, 16, 64); acc2 += __shfl_xor(acc2, 32, 64);
    acc3 += __shfl_xor(acc3, 16, 64); acc3 += __shfl_xor(acc3, 32, 64);

    if (q == 0) {
        float r0 = alpha * acc0, r1 = alpha * acc1, r2 = alpha * acc2, r3 = alpha * acc3;
        if (beta != 0.f) {
            uint2 pv = *(const uint2*)(prev + (size_t)wid * F + fb);
            float2 plo = __half22float2(*(__half2*)&pv.x);
            float2 phi = __half22float2(*(__half2*)&pv.y);
            r0 -= beta * plo.x; r1 -= beta * plo.y;
            r2 -= beta * phi.x; r3 -= beta * phi.y;
        }
        uint2 outv;
        *(__half2*)&outv.x = __floats2half2_rn(r0, r1);
        *(__half2*)&outv.y = __floats2half2_rn(r2, r3);
        *(uint2*)(dst + (size_t)wid * F + fb) = outv;
    }
}

// ---------------- fused MFMA: y = softmax(relu(sum_k Tk@W1k + b1) @ W2 + b2) ----------------
__global__ __launch_bounds__(256) void k_fused_mfma(const __half* __restrict__ T,
                                                    const __half* __restrict__ Wf,
                                                    const float* __restrict__ b1,
                                                    const float* __restrict__ W2,
                                                    const float* __restrict__ b2,
                                                    float* __restrict__ y) {
    __shared__ float Ht[64][65];
    __shared__ float W2l[64 * 16];
    __shared__ float b2l[16];
    int tid = threadIdx.x;
    int lane = tid & 63;
    int w = tid >> 6;
    int ln15 = lane & 15;
    int lg = lane >> 4;
    int base = blockIdx.x * 64;

    for (int j = tid; j < 64 * 16; j += 256) W2l[j] = W2[j];
    if (tid < 16) b2l[tid] = b2[tid];

    int nd = base + (w << 4) + ln15;
    if (nd > N_NODES - 1) nd = N_NODES - 1;  // clamp: garbage rows, stores guarded

    f32x4 acc0 = {0.f, 0.f, 0.f, 0.f};
    f32x4 acc1 = {0.f, 0.f, 0.f, 0.f};
    f32x4 acc2 = {0.f, 0.f, 0.f, 0.f};
    f32x4 acc3 = {0.f, 0.f, 0.f, 0.f};

    for (int s = 0; s < 16; s++) {
        int kidx = s >> 1;
        int fg = s & 1;
        f16x8 a = *(const f16x8*)(T + ((size_t)kidx * N_NODES + nd) * F + fg * 32 + lg * 8);
        const __half* wb = Wf + ((size_t)((kidx * 2 + fg) * 4) * 64 + lane) * 8;
        f16x8 b0 = *(const f16x8*)(wb);
        f16x8 b1f = *(const f16x8*)(wb + 64 * 8);
        f16x8 b2f = *(const f16x8*)(wb + 128 * 8);
        f16x8 b3f = *(const f16x8*)(wb + 192 * 8);
        acc0 = __builtin_amdgcn_mfma_f32_16x16x32_f16(a, b0, acc0, 0, 0, 0);
        acc1 = __builtin_amdgcn_mfma_f32_16x16x32_f16(a, b1f, acc1, 0, 0, 0);
        acc2 = __builtin_amdgcn_mfma_f32_16x16x32_f16(a, b2f, acc2, 0, 0, 0);
        acc3 = __builtin_amdgcn_mfma_f32_16x16x32_f16(a, b3f, acc3, 0, 0, 0);
    }

    int hrow = (w << 4) + (lg << 2);
    {
        float bb0 = b1[0 * 16 + ln15];
        float bb1 = b1[1 * 16 + ln15];
        float bb2 = b1[2 * 16 + ln15];
        float bb3 = b1[3 * 16 + ln15];
#pragma unroll
        for (int r = 0; r < 4; r++) {
            float h0 = acc0[r] + bb0;
            float h1 = acc1[r] + bb1;
            float h2 = acc2[r] + bb2;
            float h3 = acc3[r] + bb3;
            Ht[hrow + r][0 * 16 + ln15] = h0 > 0.f ? h0 : 0.f;
            Ht[hrow + r][1 * 16 + ln15] = h1 > 0.f ? h1 : 0.f;
            Ht[hrow + r][2 * 16 + ln15] = h2 > 0.f ? h2 : 0.f;
            Ht[hrow + r][3 * 16 + ln15] = h3 > 0.f ? h3 : 0.f;
        }
    }
    __syncthreads();

    int node = tid >> 2;
    int cg = tid & 3;
    int gnode = base + node;
    if (gnode >= N_NODES) return;
    float l0 = b2l[cg * 4 + 0], l1 = b2l[cg * 4 + 1], l2 = b2l[cg * 4 + 2], l3 = b2l[cg * 4 + 3];
    for (int f = 0; f < 64; f++) {
        float h = Ht[node][f];
        l0 = fmaf(h, W2l[f * 16 + cg * 4 + 0], l0);
        l1 = fmaf(h, W2l[f * 16 + cg * 4 + 1], l1);
        l2 = fmaf(h, W2l[f * 16 + cg * 4 + 2], l2);
        l3 = fmaf(h, W2l[f * 16 + cg * 4 + 3], l3);
    }
    float m = fmaxf(fmaxf(l0, l1), fmaxf(l2, l3));
    m = fmaxf(m, __shfl_xor(m, 1, 64));
    m = fmaxf(m, __shfl_xor(m, 2, 64));
    float e0 = expf(l0 - m), e1 = expf(l1 - m), e2 = expf(l2 - m), e3 = expf(l3 - m);
    float s = e0 + e1 + e2 + e3;
    s += __shfl_xor(s, 1, 64);
    s += __shfl_xor(s, 2, 64);
    float inv = 1.f / s;
    float4 o = make_float4(e0 * inv, e1 * inv, e2 * inv, e3 * inv);
    *(float4*)&y[(size_t)gnode * 16 + cg * 4] = o;
}

// ---------------- launch ----------------

extern "C" void kernel_launch(void* const* d_in, const int* in_sizes, int n_in,
                              void* d_out, int out_size, void* d_ws, size_t ws_size,
                              hipStream_t stream) {
    const float* x  = (const float*)d_in[0];
    const int*   ei = (const int*)d_in[1];
    const float* W1 = (const float*)d_in[2];
    const float* b1 = (const float*)d_in[3];
    const float* W2 = (const float*)d_in[4];
    const float* b2 = (const float*)d_in[5];
    float* y = (float*)d_out;

    char* p = (char*)d_ws;
    auto alloc = [&](size_t bytes) {
        char* q = p;
        p += (bytes + 255) & ~(size_t)255;
        return q;
    };
    int*   deg    = (int*)alloc((size_t)N_NODES * 4);
    float* dinv   = (float*)alloc((size_t)N_NODES * 4);
    int*   rowptr = (int*)alloc((size_t)(N_NODES + 1) * 4);
    int*   bsum   = (int*)alloc(128 * 4);
    int*   gcur   = (int*)alloc(256 * 4);
    int2*  csr_ew = (int2*)alloc((size_t)N_EDGES * 8);
    __half* T     = (__half*)alloc((size_t)K1 * N_NODES * F * 2);
    __half* Wf    = (__half*)alloc((size_t)K1 * 2 * 4 * 64 * 8 * 2);

    // bucket buffer (196*9216*8B = 14.5 MB) aliases T: dead before k_cvt/k_prop write T.
    int2* bk = (int2*)T;

    hipMemsetAsync(gcur, 0, 256 * 4, stream);

    k_bucketA<<<(N_EDGES + 1023) / 1024, 256, 0, stream>>>(ei, gcur, bk);
    k_degB<<<NBK, 256, 0, stream>>>(bk, gcur, deg, dinv);
    int nblk = (N_NODES + 1023) / 1024;
    k_scan1<<<nblk, 256, 0, stream>>>(deg, rowptr, bsum);
    k_scan2<<<1, 64, 0, stream>>>(bsum, rowptr, nblk);
    k_scan3<<<nblk, 256, 0, stream>>>(rowptr, bsum);
    k_fillB<<<NBK, 256, 0, stream>>>(bk, gcur, rowptr, dinv, csr_ew);
    k_prepW<<<16, 256, 0, stream>>>(W1, Wf);

    const size_t TSZ = (size_t)N_NODES * F;
    __half* Tk[K1];
    for (int k = 0; k < K1; k++) Tk[k] = T + (size_t)k * TSZ;

    k_cvt<<<(N_NODES * F / 4 + 255) / 256, 256, 0, stream>>>(x, Tk[0]);

    int prop_blocks = (N_NODES + 3) / 4;
    k_prop<<<prop_blocks, 256, 0, stream>>>(rowptr, csr_ew, Tk[0], Tk[0], Tk[1], 1.f, 0.f);
    for (int k = 2; k < K1; k++)
        k_prop<<<prop_blocks, 256, 0, stream>>>(rowptr, csr_ew, Tk[k - 1], Tk[k - 2], Tk[k], 2.f, 1.f);

    int gemm_blocks = (N_NODES + 63) / 64;
    k_fused_mfma<<<gemm_blocks, 256, 0, stream>>>(T, Wf, b1, W2, b2, y);
}

// Round 12
// 344.872 us; speedup vs baseline: 1.7286x; 1.1771x over previous
//
#include <hip/hip_runtime.h>
#include <hip/hip_fp16.h>

#define N_NODES 100000
#define N_EDGES 1600000
#define F 64
#define NCLS 16
#define K1 8
#define BSH 9                  // bucket = row >> 9  (512 rows)
#define NBK 196                // ceil(100000 / 512)
#define BROWS 512
#define BKCAP 9216             // mean 8192 + ~11 sigma
#define EPB 4096               // bucketA edges per block

using f16x8 = __attribute__((ext_vector_type(8))) _Float16;
using f32x4 = __attribute__((ext_vector_type(4))) float;

// ---------------- pass A: bucket edges, per-wave LDS counters, 4096 edges/block ----------------
__global__ __launch_bounds__(256) void k_bucketA(const int* __restrict__ ei,
                                                 int* __restrict__ gcur,
                                                 int2* __restrict__ bk) {
    __shared__ int cnt[4][256];
    __shared__ int wbase[4][256];
    int tid = threadIdx.x;
    int w = tid >> 6;
    for (int i = tid; i < 1024; i += 256) ((int*)cnt)[i] = 0;
    __syncthreads();
    int packed[16];
    int e0 = blockIdx.x * EPB;
#pragma unroll
    for (int u = 0; u < 16; u++) {
        int e = e0 + u * 256 + tid;
        packed[u] = -1;
        if (e < N_EDGES) {
            int r = ei[e], c = ei[N_EDGES + e];
            if (r != c) {
                int b = r >> BSH;
                int rank = atomicAdd(&cnt[w][b], 1);
                packed[u] = (rank << 8) | b;
            }
        }
    }
    __syncthreads();
    {
        int c0 = cnt[0][tid], c1 = cnt[1][tid], c2 = cnt[2][tid], c3 = cnt[3][tid];
        int tot = c0 + c1 + c2 + c3;
        int g = tot ? atomicAdd(&gcur[tid], tot) : 0;
        wbase[0][tid] = g;
        wbase[1][tid] = g + c0;
        wbase[2][tid] = g + c0 + c1;
        wbase[3][tid] = g + c0 + c1 + c2;
    }
    __syncthreads();
#pragma unroll
    for (int u = 0; u < 16; u++) {
        if (packed[u] >= 0) {
            int e = e0 + u * 256 + tid;
            int r = ei[e], c = ei[N_EDGES + e];   // L1/L2-hot re-read
            int b = packed[u] & 255;
            int rank = packed[u] >> 8;
            bk[(size_t)b * BKCAP + wbase[w][b] + rank] = make_int2(r, c);
        }
    }
}

// ---------------- pass B1: per-bucket degree histogram + dinv (fused) ----------------
__global__ __launch_bounds__(256) void k_degB(const int2* __restrict__ bk,
                                              const int* __restrict__ gcur,
                                              int* __restrict__ deg,
                                              float* __restrict__ dinv) {
    __shared__ int hist[BROWS];
    int b = blockIdx.x;
    for (int i = threadIdx.x; i < BROWS; i += 256) hist[i] = 0;
    __syncthreads();
    int cnt = gcur[b];
    const int2* src = bk + (size_t)b * BKCAP;
    for (int i = threadIdx.x; i < cnt; i += 256)
        atomicAdd(&hist[src[i].x & (BROWS - 1)], 1);
    __syncthreads();
    int rbase = b << BSH;
    for (int i = threadIdx.x; i < BROWS; i += 256) {
        int gr = rbase + i;
        if (gr < N_NODES) {
            int d = hist[i];
            deg[gr] = d;
            dinv[gr] = d > 0 ? rsqrtf((float)d) : 0.f;
        }
    }
}

// ---------------- exclusive scan (rowptr) ----------------
__global__ void k_scan1(const int* __restrict__ deg, int* __restrict__ rowptr, int* __restrict__ bsum) {
    __shared__ int sd[256];
    int tid = threadIdx.x;
    int base = blockIdx.x * 1024 + tid * 4;
    int v[4];
#pragma unroll
    for (int j = 0; j < 4; j++) {
        int idx = base + j;
        v[j] = (idx < N_NODES) ? deg[idx] : 0;
    }
    int s = v[0] + v[1] + v[2] + v[3];
    sd[tid] = s;
    __syncthreads();
    for (int d = 1; d < 256; d <<= 1) {
        int t = (tid >= d) ? sd[tid - d] : 0;
        __syncthreads();
        sd[tid] += t;
        __syncthreads();
    }
    int excl = sd[tid] - s;
    if (tid == 255) bsum[blockIdx.x] = sd[255];
    int run = excl;
#pragma unroll
    for (int j = 0; j < 4; j++) {
        int idx = base + j;
        if (idx < N_NODES) rowptr[idx] = run;
        run += v[j];
    }
}

__global__ void k_scan2(int* __restrict__ bsum, int* __restrict__ rowptr, int nblk) {
    if (threadIdx.x == 0 && blockIdx.x == 0) {
        int acc = 0;
        for (int b = 0; b < nblk; b++) { int t = bsum[b]; bsum[b] = acc; acc += t; }
        rowptr[N_NODES] = acc;
    }
}

__global__ void k_scan3(int* __restrict__ rowptr, const int* __restrict__ bsum) {
    int tid = threadIdx.x;
    int base = blockIdx.x * 1024 + tid * 4;
    int off = bsum[blockIdx.x];
#pragma unroll
    for (int j = 0; j < 4; j++) {
        int idx = base + j;
        if (idx < N_NODES) rowptr[idx] += off;
    }
}

// ---------------- pass B2: bucket -> CSR, one block per bucket, LDS row-cursors ----------------
__global__ __launch_bounds__(256) void k_fillB(const int2* __restrict__ bk,
                                               const int* __restrict__ gcur,
                                               const int* __restrict__ rowptr,
                                               const float* __restrict__ dinv,
                                               int2* __restrict__ csr_ew) {
    __shared__ int cur[BROWS];
    int b = blockIdx.x;
    for (int i = threadIdx.x; i < BROWS; i += 256) cur[i] = 0;
    __syncthreads();
    int cnt = gcur[b];
    const int2* src = bk + (size_t)b * BKCAP;
    for (int i = threadIdx.x; i < cnt; i += 256) {
        int2 rc = src[i];
        int rank = atomicAdd(&cur[rc.x & (BROWS - 1)], 1);
        float w = -dinv[rc.x] * dinv[rc.y];
        csr_ew[rowptr[rc.x] + rank] = make_int2(rc.y, __float_as_int(w));
    }
}

// ---------------- x fp32 -> fp16 ----------------
__global__ void k_cvt(const float* __restrict__ x, __half* __restrict__ t0) {
    int i = blockIdx.x * blockDim.x + threadIdx.x;
    int base = i * 4;
    if (base >= N_NODES * F) return;
    float4 v = *(const float4*)&x[base];
    __half2 a = __floats2half2_rn(v.x, v.y);
    __half2 b = __floats2half2_rn(v.z, v.w);
    *(__half2*)&t0[base] = a;
    *(__half2*)&t0[base + 2] = b;
}

// ---------------- W1 -> fp16 B-fragment layout ----------------
__global__ void k_prepW(const float* __restrict__ W1, __half* __restrict__ Wf) {
    int t = blockIdx.x * blockDim.x + threadIdx.x;
    if (t >= K1 * 2 * 4 * 64) return;
    int lane = t & 63;
    int cb = (t >> 6) & 3;
    int fg = (t >> 8) & 1;
    int kidx = t >> 9;
    int col = cb * 16 + (lane & 15);
    int kbase = fg * 32 + (lane >> 4) * 8;
    f16x8 v;
#pragma unroll
    for (int j = 0; j < 8; j++)
        v[j] = (_Float16)W1[kidx * 4096 + (kbase + j) * 64 + col];
    *(f16x8*)(Wf + (size_t)t * 8) = v;
}

// ---------------- propagation: 2 nodes/wave, 8 wide gathers in flight ----------------
// half h = lane>>5 owns node nA+h; oct q2 = (lane>>4)&1 selects row slot;
// 16 lanes x 8 B cover one 128 B row. One load instr fetches 4 rows (2/node).
// Burst of 16 edges/node = 8 independent load instructions.
__global__ __launch_bounds__(256) void k_prop(const int* __restrict__ rowptr,
                                              const int2* __restrict__ csr_ew,
                                              const __half* __restrict__ src,
                                              const __half* __restrict__ prev,
                                              __half* __restrict__ dst,
                                              float alpha, float beta) {
    int wpair = (int)((blockIdx.x * blockDim.x + threadIdx.x) >> 6);
    int lane = threadIdx.x & 63;
    int nA = wpair * 2;
    if (nA >= N_NODES) return;
    int h = lane >> 5;           // 0 = node A, 1 = node B
    int hl = lane & 31;
    int q2 = (lane >> 4) & 1;    // oct within half
    int fb = (lane & 15) * 4;    // feature base (4 fp16 = 8 B)
    int node = nA + h;
    bool valid = node < N_NODES;
    int cb  = valid ? rowptr[node] : 0;
    int end = valid ? rowptr[node + 1] : 0;

    float acc0 = 0.f, acc1 = 0.f, acc2 = 0.f, acc3 = 0.f;

    while (true) {
        int n_own = end - cb;
        if (n_own > 32) n_own = 32;
        if (n_own < 0) n_own = 0;
        int n_oth = __shfl(n_own, lane ^ 32, 64);
        int nmax = n_own > n_oth ? n_own : n_oth;
        if (nmax == 0) break;
        int2 e = make_int2(0, 0);
        if (hl < n_own) e = csr_ew[cb + hl];
        for (int j = 0; j < nmax; j += 16) {
            int cc[8];
            float ww[8];
#pragma unroll
            for (int g = 0; g < 8; g++) {
                int sl = (h << 5) | (j + g * 2 + q2);
                cc[g] = __shfl(e.x, sl, 64);
                ww[g] = __int_as_float(__shfl(e.y, sl, 64));
            }
            uint2 raw[8];
#pragma unroll
            for (int g = 0; g < 8; g++)
                raw[g] = *(const uint2*)(src + (size_t)cc[g] * F + fb);
#pragma unroll
            for (int g = 0; g < 8; g++) {
                float2 lo = __half22float2(*(__half2*)&raw[g].x);
                float2 hi = __half22float2(*(__half2*)&raw[g].y);
                acc0 = fmaf(ww[g], lo.x, acc0);
                acc1 = fmaf(ww[g], lo.y, acc1);
                acc2 = fmaf(ww[g], hi.x, acc2);
                acc3 = fmaf(ww[g], hi.y, acc3);
            }
        }
        cb += n_own;
    }

    // fold oct pairs (xor 16 stays within the half, preserves lane&15)
    acc0 += __shfl_xor(acc0, 16, 64);
    acc1 += __shfl_xor(acc1, 16, 64);
    acc2 += __shfl_xor(acc2, 16, 64);
    acc3 += __shfl_xor(acc3, 16, 64);

    if (q2 == 0 && valid) {
        float r0 = alpha * acc0, r1 = alpha * acc1, r2 = alpha * acc2, r3 = alpha * acc3;
        if (beta != 0.f) {
            uint2 pv = *(const uint2*)(prev + (size_t)node * F + fb);
            float2 plo = __half22float2(*(__half2*)&pv.x);
            float2 phi = __half22float2(*(__half2*)&pv.y);
            r0 -= beta * plo.x; r1 -= beta * plo.y;
            r2 -= beta * phi.x; r3 -= beta * phi.y;
        }
        uint2 outv;
        *(__half2*)&outv.x = __floats2half2_rn(r0, r1);
        *(__half2*)&outv.y = __floats2half2_rn(r2, r3);
        *(uint2*)(dst + (size_t)node * F + fb) = outv;
    }
}

// ---------------- fused MFMA: y = softmax(relu(sum_k Tk@W1k + b1) @ W2 + b2) ----------------
__global__ __launch_bounds__(256) void k_fused_mfma(const __half* __restrict__ T,
                                                    const __half* __restrict__ Wf,
                                                    const float* __restrict__ b1,
                                                    const float* __restrict__ W2,
                                                    const float* __restrict__ b2,
                                                    float* __restrict__ y) {
    __shared__ float Ht[64][65];
    __shared__ float W2l[64 * 16];
    __shared__ float b2l[16];
    int tid = threadIdx.x;
    int lane = tid & 63;
    int w = tid >> 6;
    int ln15 = lane & 15;
    int lg = lane >> 4;
    int base = blockIdx.x * 64;

    for (int j = tid; j < 64 * 16; j += 256) W2l[j] = W2[j];
    if (tid < 16) b2l[tid] = b2[tid];

    int nd = base + (w << 4) + ln15;
    if (nd > N_NODES - 1) nd = N_NODES - 1;  // clamp: garbage rows, stores guarded

    f32x4 acc0 = {0.f, 0.f, 0.f, 0.f};
    f32x4 acc1 = {0.f, 0.f, 0.f, 0.f};
    f32x4 acc2 = {0.f, 0.f, 0.f, 0.f};
    f32x4 acc3 = {0.f, 0.f, 0.f, 0.f};

    for (int s = 0; s < 16; s++) {
        int kidx = s >> 1;
        int fg = s & 1;
        f16x8 a = *(const f16x8*)(T + ((size_t)kidx * N_NODES + nd) * F + fg * 32 + lg * 8);
        const __half* wb = Wf + ((size_t)((kidx * 2 + fg) * 4) * 64 + lane) * 8;
        f16x8 b0 = *(const f16x8*)(wb);
        f16x8 b1f = *(const f16x8*)(wb + 64 * 8);
        f16x8 b2f = *(const f16x8*)(wb + 128 * 8);
        f16x8 b3f = *(const f16x8*)(wb + 192 * 8);
        acc0 = __builtin_amdgcn_mfma_f32_16x16x32_f16(a, b0, acc0, 0, 0, 0);
        acc1 = __builtin_amdgcn_mfma_f32_16x16x32_f16(a, b1f, acc1, 0, 0, 0);
        acc2 = __builtin_amdgcn_mfma_f32_16x16x32_f16(a, b2f, acc2, 0, 0, 0);
        acc3 = __builtin_amdgcn_mfma_f32_16x16x32_f16(a, b3f, acc3, 0, 0, 0);
    }

    int hrow = (w << 4) + (lg << 2);
    {
        float bb0 = b1[0 * 16 + ln15];
        float bb1 = b1[1 * 16 + ln15];
        float bb2 = b1[2 * 16 + ln15];
        float bb3 = b1[3 * 16 + ln15];
#pragma unroll
        for (int r = 0; r < 4; r++) {
            float h0 = acc0[r] + bb0;
            float h1 = acc1[r] + bb1;
            float h2 = acc2[r] + bb2;
            float h3 = acc3[r] + bb3;
            Ht[hrow + r][0 * 16 + ln15] = h0 > 0.f ? h0 : 0.f;
            Ht[hrow + r][1 * 16 + ln15] = h1 > 0.f ? h1 : 0.f;
            Ht[hrow + r][2 * 16 + ln15] = h2 > 0.f ? h2 : 0.f;
            Ht[hrow + r][3 * 16 + ln15] = h3 > 0.f ? h3 : 0.f;
        }
    }
    __syncthreads();

    int node = tid >> 2;
    int cg = tid & 3;
    int gnode = base + node;
    if (gnode >= N_NODES) return;
    float l0 = b2l[cg * 4 + 0], l1 = b2l[cg * 4 + 1], l2 = b2l[cg * 4 + 2], l3 = b2l[cg * 4 + 3];
    for (int f = 0; f < 64; f++) {
        float h = Ht[node][f];
        l0 = fmaf(h, W2l[f * 16 + cg * 4 + 0], l0);
        l1 = fmaf(h, W2l[f * 16 + cg * 4 + 1], l1);
        l2 = fmaf(h, W2l[f * 16 + cg * 4 + 2], l2);
        l3 = fmaf(h, W2l[f * 16 + cg * 4 + 3], l3);
    }
    float m = fmaxf(fmaxf(l0, l1), fmaxf(l2, l3));
    m = fmaxf(m, __shfl_xor(m, 1, 64));
    m = fmaxf(m, __shfl_xor(m, 2, 64));
    float e0 = expf(l0 - m), e1 = expf(l1 - m), e2 = expf(l2 - m), e3 = expf(l3 - m);
    float s = e0 + e1 + e2 + e3;
    s += __shfl_xor(s, 1, 64);
    s += __shfl_xor(s, 2, 64);
    float inv = 1.f / s;
    float4 o = make_float4(e0 * inv, e1 * inv, e2 * inv, e3 * inv);
    *(float4*)&y[(size_t)gnode * 16 + cg * 4] = o;
}

// ---------------- launch ----------------

extern "C" void kernel_launch(void* const* d_in, const int* in_sizes, int n_in,
                              void* d_out, int out_size, void* d_ws, size_t ws_size,
                              hipStream_t stream) {
    const float* x  = (const float*)d_in[0];
    const int*   ei = (const int*)d_in[1];
    const float* W1 = (const float*)d_in[2];
    const float* b1 = (const float*)d_in[3];
    const float* W2 = (const float*)d_in[4];
    const float* b2 = (const float*)d_in[5];
    float* y = (float*)d_out;

    char* p = (char*)d_ws;
    auto alloc = [&](size_t bytes) {
        char* q = p;
        p += (bytes + 255) & ~(size_t)255;
        return q;
    };
    int*   deg    = (int*)alloc((size_t)N_NODES * 4);
    float* dinv   = (float*)alloc((size_t)N_NODES * 4);
    int*   rowptr = (int*)alloc((size_t)(N_NODES + 1) * 4);
    int*   bsum   = (int*)alloc(128 * 4);
    int*   gcur   = (int*)alloc(256 * 4);
    int2*  csr_ew = (int2*)alloc((size_t)N_EDGES * 8);
    __half* T     = (__half*)alloc((size_t)K1 * N_NODES * F * 2);
    __half* Wf    = (__half*)alloc((size_t)K1 * 2 * 4 * 64 * 8 * 2);

    // bucket buffer (196*9216*8B = 14.5 MB) aliases T: dead before k_cvt/k_prop write T.
    int2* bk = (int2*)T;

    hipMemsetAsync(gcur, 0, 256 * 4, stream);

    k_bucketA<<<(N_EDGES + EPB - 1) / EPB, 256, 0, stream>>>(ei, gcur, bk);
    k_degB<<<NBK, 256, 0, stream>>>(bk, gcur, deg, dinv);
    int nblk = (N_NODES + 1023) / 1024;
    k_scan1<<<nblk, 256, 0, stream>>>(deg, rowptr, bsum);
    k_scan2<<<1, 64, 0, stream>>>(bsum, rowptr, nblk);
    k_scan3<<<nblk, 256, 0, stream>>>(rowptr, bsum);
    k_fillB<<<NBK, 256, 0, stream>>>(bk, gcur, rowptr, dinv, csr_ew);
    k_prepW<<<16, 256, 0, stream>>>(W1, Wf);

    const size_t TSZ = (size_t)N_NODES * F;
    __half* Tk[K1];
    for (int k = 0; k < K1; k++) Tk[k] = T + (size_t)k * TSZ;

    k_cvt<<<(N_NODES * F / 4 + 255) / 256, 256, 0, stream>>>(x, Tk[0]);

    int npair = (N_NODES + 1) / 2;
    int prop_blocks = (npair + 3) / 4;
    k_prop<<<prop_blocks, 256, 0, stream>>>(rowptr, csr_ew, Tk[0], Tk[0], Tk[1], 1.f, 0.f);
    for (int k = 2; k < K1; k++)
        k_prop<<<prop_blocks, 256, 0, stream>>>(rowptr, csr_ew, Tk[k - 1], Tk[k - 2], Tk[k], 2.f, 1.f);

    int gemm_blocks = (N_NODES + 63) / 64;
    k_fused_mfma<<<gemm_blocks, 256, 0, stream>>>(T, Wf, b1, W2, b2, y);
}

// Round 13
// 343.179 us; speedup vs baseline: 1.7371x; 1.0049x over previous
//
#include <hip/hip_runtime.h>
#include <hip/hip_fp16.h>

#define N_NODES 100000
#define N_EDGES 1600000
#define F 64
#define NCLS 16
#define K1 8
#define BSH 9                  // bucket = row >> 9  (512 rows)
#define NBK 196                // ceil(100000 / 512)
#define BROWS 512
#define BKCAP 9216             // mean 8192 + ~11 sigma
#define EPB 4096               // bucketA edges per block

using f16x8 = __attribute__((ext_vector_type(8))) _Float16;
using f32x4 = __attribute__((ext_vector_type(4))) float;

// ---------------- pass A: bucket edges, per-wave LDS counters, 4096 edges/block ----------------
__global__ __launch_bounds__(256) void k_bucketA(const int* __restrict__ ei,
                                                 int* __restrict__ gcur,
                                                 int2* __restrict__ bk) {
    __shared__ int cnt[4][256];
    __shared__ int wbase[4][256];
    int tid = threadIdx.x;
    int w = tid >> 6;
    for (int i = tid; i < 1024; i += 256) ((int*)cnt)[i] = 0;
    __syncthreads();
    int packed[16];
    int e0 = blockIdx.x * EPB;
#pragma unroll
    for (int u = 0; u < 16; u++) {
        int e = e0 + u * 256 + tid;
        packed[u] = -1;
        if (e < N_EDGES) {
            int r = ei[e], c = ei[N_EDGES + e];
            if (r != c) {
                int b = r >> BSH;
                int rank = atomicAdd(&cnt[w][b], 1);
                packed[u] = (rank << 8) | b;
            }
        }
    }
    __syncthreads();
    {
        int c0 = cnt[0][tid], c1 = cnt[1][tid], c2 = cnt[2][tid], c3 = cnt[3][tid];
        int tot = c0 + c1 + c2 + c3;
        int g = tot ? atomicAdd(&gcur[tid], tot) : 0;
        wbase[0][tid] = g;
        wbase[1][tid] = g + c0;
        wbase[2][tid] = g + c0 + c1;
        wbase[3][tid] = g + c0 + c1 + c2;
    }
    __syncthreads();
#pragma unroll
    for (int u = 0; u < 16; u++) {
        if (packed[u] >= 0) {
            int e = e0 + u * 256 + tid;
            int r = ei[e], c = ei[N_EDGES + e];   // L1/L2-hot re-read
            int b = packed[u] & 255;
            int rank = packed[u] >> 8;
            bk[(size_t)b * BKCAP + wbase[w][b] + rank] = make_int2(r, c);
        }
    }
}

// ---------------- pass B1: per-bucket degree histogram + dinv (fused) ----------------
__global__ __launch_bounds__(256) void k_degB(const int2* __restrict__ bk,
                                              const int* __restrict__ gcur,
                                              int* __restrict__ deg,
                                              float* __restrict__ dinv) {
    __shared__ int hist[BROWS];
    int b = blockIdx.x;
    for (int i = threadIdx.x; i < BROWS; i += 256) hist[i] = 0;
    __syncthreads();
    int cnt = gcur[b];
    const int2* src = bk + (size_t)b * BKCAP;
    for (int i = threadIdx.x; i < cnt; i += 256)
        atomicAdd(&hist[src[i].x & (BROWS - 1)], 1);
    __syncthreads();
    int rbase = b << BSH;
    for (int i = threadIdx.x; i < BROWS; i += 256) {
        int gr = rbase + i;
        if (gr < N_NODES) {
            int d = hist[i];
            deg[gr] = d;
            dinv[gr] = d > 0 ? rsqrtf((float)d) : 0.f;
        }
    }
}

// ---------------- exclusive scan (rowptr) ----------------
__global__ void k_scan1(const int* __restrict__ deg, int* __restrict__ rowptr, int* __restrict__ bsum) {
    __shared__ int sd[256];
    int tid = threadIdx.x;
    int base = blockIdx.x * 1024 + tid * 4;
    int v[4];
#pragma unroll
    for (int j = 0; j < 4; j++) {
        int idx = base + j;
        v[j] = (idx < N_NODES) ? deg[idx] : 0;
    }
    int s = v[0] + v[1] + v[2] + v[3];
    sd[tid] = s;
    __syncthreads();
    for (int d = 1; d < 256; d <<= 1) {
        int t = (tid >= d) ? sd[tid - d] : 0;
        __syncthreads();
        sd[tid] += t;
        __syncthreads();
    }
    int excl = sd[tid] - s;
    if (tid == 255) bsum[blockIdx.x] = sd[255];
    int run = excl;
#pragma unroll
    for (int j = 0; j < 4; j++) {
        int idx = base + j;
        if (idx < N_NODES) rowptr[idx] = run;
        run += v[j];
    }
}

__global__ void k_scan2(int* __restrict__ bsum, int* __restrict__ rowptr, int nblk) {
    if (threadIdx.x == 0 && blockIdx.x == 0) {
        int acc = 0;
        for (int b = 0; b < nblk; b++) { int t = bsum[b]; bsum[b] = acc; acc += t; }
        rowptr[N_NODES] = acc;
    }
}

__global__ void k_scan3(int* __restrict__ rowptr, const int* __restrict__ bsum) {
    int tid = threadIdx.x;
    int base = blockIdx.x * 1024 + tid * 4;
    int off = bsum[blockIdx.x];
#pragma unroll
    for (int j = 0; j < 4; j++) {
        int idx = base + j;
        if (idx < N_NODES) rowptr[idx] += off;
    }
}

// ---------------- pass B2: bucket -> CSR, one block per bucket, LDS row-cursors ----------------
__global__ __launch_bounds__(256) void k_fillB(const int2* __restrict__ bk,
                                               const int* __restrict__ gcur,
                                               const int* __restrict__ rowptr,
                                               const float* __restrict__ dinv,
                                               int2* __restrict__ csr_ew) {
    __shared__ int cur[BROWS];
    int b = blockIdx.x;
    for (int i = threadIdx.x; i < BROWS; i += 256) cur[i] = 0;
    __syncthreads();
    int cnt = gcur[b];
    const int2* src = bk + (size_t)b * BKCAP;
    for (int i = threadIdx.x; i < cnt; i += 256) {
        int2 rc = src[i];
        int rank = atomicAdd(&cur[rc.x & (BROWS - 1)], 1);
        float w = -dinv[rc.x] * dinv[rc.y];
        csr_ew[rowptr[rc.x] + rank] = make_int2(rc.y, __float_as_int(w));
    }
}

// ---------------- x fp32 -> fp16 ----------------
__global__ void k_cvt(const float* __restrict__ x, __half* __restrict__ t0) {
    int i = blockIdx.x * blockDim.x + threadIdx.x;
    int base = i * 4;
    if (base >= N_NODES * F) return;
    float4 v = *(const float4*)&x[base];
    __half2 a = __floats2half2_rn(v.x, v.y);
    __half2 b = __floats2half2_rn(v.z, v.w);
    *(__half2*)&t0[base] = a;
    *(__half2*)&t0[base + 2] = b;
}

// ---------------- W1 -> fp16 B-fragment layout ----------------
__global__ void k_prepW(const float* __restrict__ W1, __half* __restrict__ Wf) {
    int t = blockIdx.x * blockDim.x + threadIdx.x;
    if (t >= K1 * 2 * 4 * 64) return;
    int lane = t & 63;
    int cb = (t >> 6) & 3;
    int fg = (t >> 8) & 1;
    int kidx = t >> 9;
    int col = cb * 16 + (lane & 15);
    int kbase = fg * 32 + (lane >> 4) * 8;
    f16x8 v;
#pragma unroll
    for (int j = 0; j < 8; j++)
        v[j] = (_Float16)W1[kidx * 4096 + (kbase + j) * 64 + col];
    *(f16x8*)(Wf + (size_t)t * 8) = v;
}

// ---------------- propagation: 2 nodes/wave, 8 lanes x 16 B per row ----------------
// half h = lane>>5 owns node nA+h; slot s3 = (lane>>3)&3 selects row; 8 lanes x
// uint4 cover one 128 B row -> one load instruction fetches 8 rows (4/node).
// 16-edge burst/node = 4 load instructions, 16 lines (2 KB) in flight per wave.
__global__ __launch_bounds__(256) void k_prop(const int* __restrict__ rowptr,
                                              const int2* __restrict__ csr_ew,
                                              const __half* __restrict__ src,
                                              const __half* __restrict__ prev,
                                              __half* __restrict__ dst,
                                              float alpha, float beta) {
    int wpair = (int)((blockIdx.x * blockDim.x + threadIdx.x) >> 6);
    int lane = threadIdx.x & 63;
    int nA = wpair * 2;
    if (nA >= N_NODES) return;
    int h = lane >> 5;           // 0 = node A, 1 = node B
    int hl = lane & 31;
    int s3 = (lane >> 3) & 3;    // row slot within half
    int fb = (lane & 7) * 8;     // feature base (8 fp16 = 16 B)
    int node = nA + h;
    bool valid = node < N_NODES;
    int cb  = valid ? rowptr[node] : 0;
    int end = valid ? rowptr[node + 1] : 0;

    float acc[8] = {};

    while (true) {
        int n_own = end - cb;
        if (n_own > 32) n_own = 32;
        if (n_own < 0) n_own = 0;
        int n_oth = __shfl(n_own, lane ^ 32, 64);
        int nmax = n_own > n_oth ? n_own : n_oth;
        if (nmax == 0) break;
        int2 e = make_int2(0, 0);
        if (hl < n_own) e = csr_ew[cb + hl];
        for (int j = 0; j < nmax; j += 16) {
            int cc[4];
            float ww[4];
#pragma unroll
            for (int g = 0; g < 4; g++) {
                int sl = (h << 5) | (j + g * 4 + s3);
                cc[g] = __shfl(e.x, sl, 64);
                ww[g] = __int_as_float(__shfl(e.y, sl, 64));
            }
            uint4 raw[4];
#pragma unroll
            for (int g = 0; g < 4; g++)
                raw[g] = *(const uint4*)(src + (size_t)cc[g] * F + fb);
#pragma unroll
            for (int g = 0; g < 4; g++) {
                float2 f0 = __half22float2(*(__half2*)&raw[g].x);
                float2 f1 = __half22float2(*(__half2*)&raw[g].y);
                float2 f2 = __half22float2(*(__half2*)&raw[g].z);
                float2 f3 = __half22float2(*(__half2*)&raw[g].w);
                acc[0] = fmaf(ww[g], f0.x, acc[0]);
                acc[1] = fmaf(ww[g], f0.y, acc[1]);
                acc[2] = fmaf(ww[g], f1.x, acc[2]);
                acc[3] = fmaf(ww[g], f1.y, acc[3]);
                acc[4] = fmaf(ww[g], f2.x, acc[4]);
                acc[5] = fmaf(ww[g], f2.y, acc[5]);
                acc[6] = fmaf(ww[g], f3.x, acc[6]);
                acc[7] = fmaf(ww[g], f3.y, acc[7]);
            }
        }
        cb += n_own;
    }

    // fold slots: xor 8 / xor 16 stay within the 32-lane half, preserve lane&7
#pragma unroll
    for (int i = 0; i < 8; i++) {
        acc[i] += __shfl_xor(acc[i], 8, 64);
        acc[i] += __shfl_xor(acc[i], 16, 64);
    }

    if ((lane & 24) == 0 && valid) {
        float r[8];
#pragma unroll
        for (int i = 0; i < 8; i++) r[i] = alpha * acc[i];
        if (beta != 0.f) {
            uint4 pv = *(const uint4*)(prev + (size_t)node * F + fb);
            float2 p0 = __half22float2(*(__half2*)&pv.x);
            float2 p1 = __half22float2(*(__half2*)&pv.y);
            float2 p2 = __half22float2(*(__half2*)&pv.z);
            float2 p3 = __half22float2(*(__half2*)&pv.w);
            r[0] -= beta * p0.x; r[1] -= beta * p0.y;
            r[2] -= beta * p1.x; r[3] -= beta * p1.y;
            r[4] -= beta * p2.x; r[5] -= beta * p2.y;
            r[6] -= beta * p3.x; r[7] -= beta * p3.y;
        }
        uint4 outv;
        *(__half2*)&outv.x = __floats2half2_rn(r[0], r[1]);
        *(__half2*)&outv.y = __floats2half2_rn(r[2], r[3]);
        *(__half2*)&outv.z = __floats2half2_rn(r[4], r[5]);
        *(__half2*)&outv.w = __floats2half2_rn(r[6], r[7]);
        *(uint4*)(dst + (size_t)node * F + fb) = outv;
    }
}

// ---------------- fused MFMA: y = softmax(relu(sum_k Tk@W1k + b1) @ W2 + b2) ----------------
__global__ __launch_bounds__(256) void k_fused_mfma(const __half* __restrict__ T,
                                                    const __half* __restrict__ Wf,
                                                    const float* __restrict__ b1,
                                                    const float* __restrict__ W2,
                                                    const float* __restrict__ b2,
                                                    float* __restrict__ y) {
    __shared__ float Ht[64][65];
    __shared__ float W2l[64 * 16];
    __shared__ float b2l[16];
    int tid = threadIdx.x;
    int lane = tid & 63;
    int w = tid >> 6;
    int ln15 = lane & 15;
    int lg = lane >> 4;
    int base = blockIdx.x * 64;

    for (int j = tid; j < 64 * 16; j += 256) W2l[j] = W2[j];
    if (tid < 16) b2l[tid] = b2[tid];

    int nd = base + (w << 4) + ln15;
    if (nd > N_NODES - 1) nd = N_NODES - 1;  // clamp: garbage rows, stores guarded

    f32x4 acc0 = {0.f, 0.f, 0.f, 0.f};
    f32x4 acc1 = {0.f, 0.f, 0.f, 0.f};
    f32x4 acc2 = {0.f, 0.f, 0.f, 0.f};
    f32x4 acc3 = {0.f, 0.f, 0.f, 0.f};

    for (int s = 0; s < 16; s++) {
        int kidx = s >> 1;
        int fg = s & 1;
        f16x8 a = *(const f16x8*)(T + ((size_t)kidx * N_NODES + nd) * F + fg * 32 + lg * 8);
        const __half* wb = Wf + ((size_t)((kidx * 2 + fg) * 4) * 64 + lane) * 8;
        f16x8 b0 = *(const f16x8*)(wb);
        f16x8 b1f = *(const f16x8*)(wb + 64 * 8);
        f16x8 b2f = *(const f16x8*)(wb + 128 * 8);
        f16x8 b3f = *(const f16x8*)(wb + 192 * 8);
        acc0 = __builtin_amdgcn_mfma_f32_16x16x32_f16(a, b0, acc0, 0, 0, 0);
        acc1 = __builtin_amdgcn_mfma_f32_16x16x32_f16(a, b1f, acc1, 0, 0, 0);
        acc2 = __builtin_amdgcn_mfma_f32_16x16x32_f16(a, b2f, acc2, 0, 0, 0);
        acc3 = __builtin_amdgcn_mfma_f32_16x16x32_f16(a, b3f, acc3, 0, 0, 0);
    }

    int hrow = (w << 4) + (lg << 2);
    {
        float bb0 = b1[0 * 16 + ln15];
        float bb1 = b1[1 * 16 + ln15];
        float bb2 = b1[2 * 16 + ln15];
        float bb3 = b1[3 * 16 + ln15];
#pragma unroll
        for (int r = 0; r < 4; r++) {
            float h0 = acc0[r] + bb0;
            float h1 = acc1[r] + bb1;
            float h2 = acc2[r] + bb2;
            float h3 = acc3[r] + bb3;
            Ht[hrow + r][0 * 16 + ln15] = h0 > 0.f ? h0 : 0.f;
            Ht[hrow + r][1 * 16 + ln15] = h1 > 0.f ? h1 : 0.f;
            Ht[hrow + r][2 * 16 + ln15] = h2 > 0.f ? h2 : 0.f;
            Ht[hrow + r][3 * 16 + ln15] = h3 > 0.f ? h3 : 0.f;
        }
    }
    __syncthreads();

    int node = tid >> 2;
    int cg = tid & 3;
    int gnode = base + node;
    if (gnode >= N_NODES) return;
    float l0 = b2l[cg * 4 + 0], l1 = b2l[cg * 4 + 1], l2 = b2l[cg * 4 + 2], l3 = b2l[cg * 4 + 3];
    for (int f = 0; f < 64; f++) {
        float h = Ht[node][f];
        l0 = fmaf(h, W2l[f * 16 + cg * 4 + 0], l0);
        l1 = fmaf(h, W2l[f * 16 + cg * 4 + 1], l1);
        l2 = fmaf(h, W2l[f * 16 + cg * 4 + 2], l2);
        l3 = fmaf(h, W2l[f * 16 + cg * 4 + 3], l3);
    }
    float m = fmaxf(fmaxf(l0, l1), fmaxf(l2, l3));
    m = fmaxf(m, __shfl_xor(m, 1, 64));
    m = fmaxf(m, __shfl_xor(m, 2, 64));
    float e0 = expf(l0 - m), e1 = expf(l1 - m), e2 = expf(l2 - m), e3 = expf(l3 - m);
    float s = e0 + e1 + e2 + e3;
    s += __shfl_xor(s, 1, 64);
    s += __shfl_xor(s, 2, 64);
    float inv = 1.f / s;
    float4 o = make_float4(e0 * inv, e1 * inv, e2 * inv, e3 * inv);
    *(float4*)&y[(size_t)gnode * 16 + cg * 4] = o;
}

// ---------------- launch ----------------

extern "C" void kernel_launch(void* const* d_in, const int* in_sizes, int n_in,
                              void* d_out, int out_size, void* d_ws, size_t ws_size,
                              hipStream_t stream) {
    const float* x  = (const float*)d_in[0];
    const int*   ei = (const int*)d_in[1];
    const float* W1 = (const float*)d_in[2];
    const float* b1 = (const float*)d_in[3];
    const float* W2 = (const float*)d_in[4];
    const float* b2 = (const float*)d_in[5];
    float* y = (float*)d_out;

    char* p = (char*)d_ws;
    auto alloc = [&](size_t bytes) {
        char* q = p;
        p += (bytes + 255) & ~(size_t)255;
        return q;
    };
    int*   deg    = (int*)alloc((size_t)N_NODES * 4);
    float* dinv   = (float*)alloc((size_t)N_NODES * 4);
    int*   rowptr = (int*)alloc((size_t)(N_NODES + 1) * 4);
    int*   bsum   = (int*)alloc(128 * 4);
    int*   gcur   = (int*)alloc(256 * 4);
    int2*  csr_ew = (int2*)alloc((size_t)N_EDGES * 8);
    __half* T     = (__half*)alloc((size_t)K1 * N_NODES * F * 2);
    __half* Wf    = (__half*)alloc((size_t)K1 * 2 * 4 * 64 * 8 * 2);

    // bucket buffer (196*9216*8B = 14.5 MB) aliases T: dead before k_cvt/k_prop write T.
    int2* bk = (int2*)T;

    hipMemsetAsync(gcur, 0, 256 * 4, stream);

    k_bucketA<<<(N_EDGES + EPB - 1) / EPB, 256, 0, stream>>>(ei, gcur, bk);
    k_degB<<<NBK, 256, 0, stream>>>(bk, gcur, deg, dinv);
    int nblk = (N_NODES + 1023) / 1024;
    k_scan1<<<nblk, 256, 0, stream>>>(deg, rowptr, bsum);
    k_scan2<<<1, 64, 0, stream>>>(bsum, rowptr, nblk);
    k_scan3<<<nblk, 256, 0, stream>>>(rowptr, bsum);
    k_fillB<<<NBK, 256, 0, stream>>>(bk, gcur, rowptr, dinv, csr_ew);
    k_prepW<<<16, 256, 0, stream>>>(W1, Wf);

    const size_t TSZ = (size_t)N_NODES * F;
    __half* Tk[K1];
    for (int k = 0; k < K1; k++) Tk[k] = T + (size_t)k * TSZ;

    k_cvt<<<(N_NODES * F / 4 + 255) / 256, 256, 0, stream>>>(x, Tk[0]);

    int npair = (N_NODES + 1) / 2;
    int prop_blocks = (npair + 3) / 4;
    k_prop<<<prop_blocks, 256, 0, stream>>>(rowptr, csr_ew, Tk[0], Tk[0], Tk[1], 1.f, 0.f);
    for (int k = 2; k < K1; k++)
        k_prop<<<prop_blocks, 256, 0, stream>>>(rowptr, csr_ew, Tk[k - 1], Tk[k - 2], Tk[k], 2.f, 1.f);

    int gemm_blocks = (N_NODES + 63) / 64;
    k_fused_mfma<<<gemm_blocks, 256, 0, stream>>>(T, Wf, b1, W2, b2, y);
}

// Round 14
// 324.570 us; speedup vs baseline: 1.8367x; 1.0573x over previous
//
#include <hip/hip_runtime.h>
#include <hip/hip_fp16.h>

#define N_NODES 100000
#define N_EDGES 1600000
#define F 64
#define NCLS 16
#define K1 8
#define BSH 9                  // bucket = row >> 9  (512 rows)
#define NBK 196                // ceil(100000 / 512)
#define BROWS 512
#define BKCAP 9216             // mean 8192 + ~11 sigma
#define EPB 4096               // bucketA edges per block

using f16x8 = __attribute__((ext_vector_type(8))) _Float16;
using f32x4 = __attribute__((ext_vector_type(4))) float;

// ---------------- pass A: bucket edges, per-wave LDS counters, regs keep (r,c) ----------------
__global__ __launch_bounds__(256) void k_bucketA(const int* __restrict__ ei,
                                                 int* __restrict__ gcur,
                                                 int2* __restrict__ bk) {
    __shared__ int cnt[4][256];
    __shared__ int wbase[4][256];
    int tid = threadIdx.x;
    int w = tid >> 6;
    for (int i = tid; i < 1024; i += 256) ((int*)cnt)[i] = 0;
    __syncthreads();
    int rv[16], cv[16], packed[16];
    int e0 = blockIdx.x * EPB;
#pragma unroll
    for (int u = 0; u < 16; u++) {
        int e = e0 + u * 256 + tid;
        packed[u] = -1;
        if (e < N_EDGES) {
            rv[u] = ei[e];
            cv[u] = ei[N_EDGES + e];
            if (rv[u] != cv[u]) {
                int b = rv[u] >> BSH;
                int rank = atomicAdd(&cnt[w][b], 1);
                packed[u] = (rank << 8) | b;
            }
        }
    }
    __syncthreads();
    {
        int c0 = cnt[0][tid], c1 = cnt[1][tid], c2 = cnt[2][tid], c3 = cnt[3][tid];
        int tot = c0 + c1 + c2 + c3;
        int g = tot ? atomicAdd(&gcur[tid], tot) : 0;
        wbase[0][tid] = g;
        wbase[1][tid] = g + c0;
        wbase[2][tid] = g + c0 + c1;
        wbase[3][tid] = g + c0 + c1 + c2;
    }
    __syncthreads();
#pragma unroll
    for (int u = 0; u < 16; u++) {
        if (packed[u] >= 0) {
            int b = packed[u] & 255;
            int rank = packed[u] >> 8;
            bk[(size_t)b * BKCAP + wbase[w][b] + rank] = make_int2(rv[u], cv[u]);
        }
    }
}

// ---------------- pass B1: per-bucket histogram + dinv + LOCAL-scan rowptr ----------------
// rowptr[gr] = b*BKCAP + exclusive_scan_within_bucket  (no global scan needed;
// prop computes end = rowptr[node] + deg[node])
__global__ __launch_bounds__(256) void k_degB(const int2* __restrict__ bk,
                                              const int* __restrict__ gcur,
                                              int* __restrict__ deg,
                                              float* __restrict__ dinv,
                                              int* __restrict__ rowptr) {
    __shared__ int hist[BROWS];
    __shared__ int sd[256];
    int b = blockIdx.x;
    int tid = threadIdx.x;
    for (int i = tid; i < BROWS; i += 256) hist[i] = 0;
    __syncthreads();
    int cnt = gcur[b];
    const int2* src = bk + (size_t)b * BKCAP;
    for (int i = tid; i < cnt; i += 256)
        atomicAdd(&hist[src[i].x & (BROWS - 1)], 1);
    __syncthreads();
    // exclusive scan over 512 entries: 2 per thread
    int v0 = hist[2 * tid], v1 = hist[2 * tid + 1];
    int s = v0 + v1;
    sd[tid] = s;
    __syncthreads();
    for (int d = 1; d < 256; d <<= 1) {
        int t = (tid >= d) ? sd[tid - d] : 0;
        __syncthreads();
        sd[tid] += t;
        __syncthreads();
    }
    int excl = sd[tid] - s;
    int rbase = b << BSH;
    int cbase = b * BKCAP;
    int gr0 = rbase + 2 * tid;
    int gr1 = gr0 + 1;
    if (gr0 < N_NODES) {
        deg[gr0] = v0;
        dinv[gr0] = v0 > 0 ? rsqrtf((float)v0) : 0.f;
        rowptr[gr0] = cbase + excl;
    }
    if (gr1 < N_NODES) {
        deg[gr1] = v1;
        dinv[gr1] = v1 > 0 ? rsqrtf((float)v1) : 0.f;
        rowptr[gr1] = cbase + excl + v0;
    }
}

// ---------------- pass B2: bucket -> CSR, one block per bucket, LDS row-cursors ----------------
__global__ __launch_bounds__(256) void k_fillB(const int2* __restrict__ bk,
                                               const int* __restrict__ gcur,
                                               const int* __restrict__ rowptr,
                                               const float* __restrict__ dinv,
                                               int2* __restrict__ csr_ew) {
    __shared__ int cur[BROWS];
    int b = blockIdx.x;
    for (int i = threadIdx.x; i < BROWS; i += 256) cur[i] = 0;
    __syncthreads();
    int cnt = gcur[b];
    const int2* src = bk + (size_t)b * BKCAP;
    for (int i = threadIdx.x; i < cnt; i += 256) {
        int2 rc = src[i];
        int rank = atomicAdd(&cur[rc.x & (BROWS - 1)], 1);
        float w = -dinv[rc.x] * dinv[rc.y];
        csr_ew[rowptr[rc.x] + rank] = make_int2(rc.y, __float_as_int(w));
    }
}

// ---------------- x fp32 -> fp16 ----------------
__global__ void k_cvt(const float* __restrict__ x, __half* __restrict__ t0) {
    int i = blockIdx.x * blockDim.x + threadIdx.x;
    int base = i * 4;
    if (base >= N_NODES * F) return;
    float4 v = *(const float4*)&x[base];
    __half2 a = __floats2half2_rn(v.x, v.y);
    __half2 b = __floats2half2_rn(v.z, v.w);
    *(__half2*)&t0[base] = a;
    *(__half2*)&t0[base + 2] = b;
}

// ---------------- W1 -> fp16 B-fragment layout ----------------
__global__ void k_prepW(const float* __restrict__ W1, __half* __restrict__ Wf) {
    int t = blockIdx.x * blockDim.x + threadIdx.x;
    if (t >= K1 * 2 * 4 * 64) return;
    int lane = t & 63;
    int cb = (t >> 6) & 3;
    int fg = (t >> 8) & 1;
    int kidx = t >> 9;
    int col = cb * 16 + (lane & 15);
    int kbase = fg * 32 + (lane >> 4) * 8;
    f16x8 v;
#pragma unroll
    for (int j = 0; j < 8; j++)
        v[j] = (_Float16)W1[kidx * 4096 + (kbase + j) * 64 + col];
    *(f16x8*)(Wf + (size_t)t * 8) = v;
}

// ---------------- propagation: 2 nodes/wave, 8 lanes x 16 B per row ----------------
__global__ __launch_bounds__(256) void k_prop(const int* __restrict__ rowptr,
                                              const int* __restrict__ deg,
                                              const int2* __restrict__ csr_ew,
                                              const __half* __restrict__ src,
                                              const __half* __restrict__ prev,
                                              __half* __restrict__ dst,
                                              float alpha, float beta) {
    int wpair = (int)((blockIdx.x * blockDim.x + threadIdx.x) >> 6);
    int lane = threadIdx.x & 63;
    int nA = wpair * 2;
    if (nA >= N_NODES) return;
    int h = lane >> 5;           // 0 = node A, 1 = node B
    int hl = lane & 31;
    int s3 = (lane >> 3) & 3;    // row slot within half
    int fb = (lane & 7) * 8;     // feature base (8 fp16 = 16 B)
    int node = nA + h;
    bool valid = node < N_NODES;
    int cb  = valid ? rowptr[node] : 0;
    int end = valid ? cb + deg[node] : 0;

    float acc[8] = {};

    while (true) {
        int n_own = end - cb;
        if (n_own > 32) n_own = 32;
        if (n_own < 0) n_own = 0;
        int n_oth = __shfl(n_own, lane ^ 32, 64);
        int nmax = n_own > n_oth ? n_own : n_oth;
        if (nmax == 0) break;
        int2 e = make_int2(0, 0);
        if (hl < n_own) e = csr_ew[cb + hl];
        for (int j = 0; j < nmax; j += 16) {
            int cc[4];
            float ww[4];
#pragma unroll
            for (int g = 0; g < 4; g++) {
                int sl = (h << 5) | (j + g * 4 + s3);
                cc[g] = __shfl(e.x, sl, 64);
                ww[g] = __int_as_float(__shfl(e.y, sl, 64));
            }
            uint4 raw[4];
#pragma unroll
            for (int g = 0; g < 4; g++)
                raw[g] = *(const uint4*)(src + (size_t)cc[g] * F + fb);
#pragma unroll
            for (int g = 0; g < 4; g++) {
                float2 f0 = __half22float2(*(__half2*)&raw[g].x);
                float2 f1 = __half22float2(*(__half2*)&raw[g].y);
                float2 f2 = __half22float2(*(__half2*)&raw[g].z);
                float2 f3 = __half22float2(*(__half2*)&raw[g].w);
                acc[0] = fmaf(ww[g], f0.x, acc[0]);
                acc[1] = fmaf(ww[g], f0.y, acc[1]);
                acc[2] = fmaf(ww[g], f1.x, acc[2]);
                acc[3] = fmaf(ww[g], f1.y, acc[3]);
                acc[4] = fmaf(ww[g], f2.x, acc[4]);
                acc[5] = fmaf(ww[g], f2.y, acc[5]);
                acc[6] = fmaf(ww[g], f3.x, acc[6]);
                acc[7] = fmaf(ww[g], f3.y, acc[7]);
            }
        }
        cb += n_own;
    }

    // fold slots: xor 8 / xor 16 stay within the 32-lane half, preserve lane&7
#pragma unroll
    for (int i = 0; i < 8; i++) {
        acc[i] += __shfl_xor(acc[i], 8, 64);
        acc[i] += __shfl_xor(acc[i], 16, 64);
    }

    if ((lane & 24) == 0 && valid) {
        float r[8];
#pragma unroll
        for (int i = 0; i < 8; i++) r[i] = alpha * acc[i];
        if (beta != 0.f) {
            uint4 pv = *(const uint4*)(prev + (size_t)node * F + fb);
            float2 p0 = __half22float2(*(__half2*)&pv.x);
            float2 p1 = __half22float2(*(__half2*)&pv.y);
            float2 p2 = __half22float2(*(__half2*)&pv.z);
            float2 p3 = __half22float2(*(__half2*)&pv.w);
            r[0] -= beta * p0.x; r[1] -= beta * p0.y;
            r[2] -= beta * p1.x; r[3] -= beta * p1.y;
            r[4] -= beta * p2.x; r[5] -= beta * p2.y;
            r[6] -= beta * p3.x; r[7] -= beta * p3.y;
        }
        uint4 outv;
        *(__half2*)&outv.x = __floats2half2_rn(r[0], r[1]);
        *(__half2*)&outv.y = __floats2half2_rn(r[2], r[3]);
        *(__half2*)&outv.z = __floats2half2_rn(r[4], r[5]);
        *(__half2*)&outv.w = __floats2half2_rn(r[6], r[7]);
        *(uint4*)(dst + (size_t)node * F + fb) = outv;
    }
}

// ---------------- fused MFMA: y = softmax(relu(sum_k Tk@W1k + b1) @ W2 + b2) ----------------
__global__ __launch_bounds__(256) void k_fused_mfma(const __half* __restrict__ T,
                                                    const __half* __restrict__ Wf,
                                                    const float* __restrict__ b1,
                                                    const float* __restrict__ W2,
                                                    const float* __restrict__ b2,
                                                    float* __restrict__ y) {
    __shared__ float Ht[64][65];
    __shared__ float W2l[64 * 16];
    __shared__ float b2l[16];
    int tid = threadIdx.x;
    int lane = tid & 63;
    int w = tid >> 6;
    int ln15 = lane & 15;
    int lg = lane >> 4;
    int base = blockIdx.x * 64;

    for (int j = tid; j < 64 * 16; j += 256) W2l[j] = W2[j];
    if (tid < 16) b2l[tid] = b2[tid];

    int nd = base + (w << 4) + ln15;
    if (nd > N_NODES - 1) nd = N_NODES - 1;  // clamp: garbage rows, stores guarded

    f32x4 acc0 = {0.f, 0.f, 0.f, 0.f};
    f32x4 acc1 = {0.f, 0.f, 0.f, 0.f};
    f32x4 acc2 = {0.f, 0.f, 0.f, 0.f};
    f32x4 acc3 = {0.f, 0.f, 0.f, 0.f};

    for (int s = 0; s < 16; s++) {
        int kidx = s >> 1;
        int fg = s & 1;
        f16x8 a = *(const f16x8*)(T + ((size_t)kidx * N_NODES + nd) * F + fg * 32 + lg * 8);
        const __half* wb = Wf + ((size_t)((kidx * 2 + fg) * 4) * 64 + lane) * 8;
        f16x8 b0 = *(const f16x8*)(wb);
        f16x8 b1f = *(const f16x8*)(wb + 64 * 8);
        f16x8 b2f = *(const f16x8*)(wb + 128 * 8);
        f16x8 b3f = *(const f16x8*)(wb + 192 * 8);
        acc0 = __builtin_amdgcn_mfma_f32_16x16x32_f16(a, b0, acc0, 0, 0, 0);
        acc1 = __builtin_amdgcn_mfma_f32_16x16x32_f16(a, b1f, acc1, 0, 0, 0);
        acc2 = __builtin_amdgcn_mfma_f32_16x16x32_f16(a, b2f, acc2, 0, 0, 0);
        acc3 = __builtin_amdgcn_mfma_f32_16x16x32_f16(a, b3f, acc3, 0, 0, 0);
    }

    int hrow = (w << 4) + (lg << 2);
    {
        float bb0 = b1[0 * 16 + ln15];
        float bb1 = b1[1 * 16 + ln15];
        float bb2 = b1[2 * 16 + ln15];
        float bb3 = b1[3 * 16 + ln15];
#pragma unroll
        for (int r = 0; r < 4; r++) {
            float h0 = acc0[r] + bb0;
            float h1 = acc1[r] + bb1;
            float h2 = acc2[r] + bb2;
            float h3 = acc3[r] + bb3;
            Ht[hrow + r][0 * 16 + ln15] = h0 > 0.f ? h0 : 0.f;
            Ht[hrow + r][1 * 16 + ln15] = h1 > 0.f ? h1 : 0.f;
            Ht[hrow + r][2 * 16 + ln15] = h2 > 0.f ? h2 : 0.f;
            Ht[hrow + r][3 * 16 + ln15] = h3 > 0.f ? h3 : 0.f;
        }
    }
    __syncthreads();

    int node = tid >> 2;
    int cg = tid & 3;
    int gnode = base + node;
    if (gnode >= N_NODES) return;
    float l0 = b2l[cg * 4 + 0], l1 = b2l[cg * 4 + 1], l2 = b2l[cg * 4 + 2], l3 = b2l[cg * 4 + 3];
    for (int f = 0; f < 64; f++) {
        float h = Ht[node][f];
        l0 = fmaf(h, W2l[f * 16 + cg * 4 + 0], l0);
        l1 = fmaf(h, W2l[f * 16 + cg * 4 + 1], l1);
        l2 = fmaf(h, W2l[f * 16 + cg * 4 + 2], l2);
        l3 = fmaf(h, W2l[f * 16 + cg * 4 + 3], l3);
    }
    float m = fmaxf(fmaxf(l0, l1), fmaxf(l2, l3));
    m = fmaxf(m, __shfl_xor(m, 1, 64));
    m = fmaxf(m, __shfl_xor(m, 2, 64));
    float e0 = expf(l0 - m), e1 = expf(l1 - m), e2 = expf(l2 - m), e3 = expf(l3 - m);
    float s = e0 + e1 + e2 + e3;
    s += __shfl_xor(s, 1, 64);
    s += __shfl_xor(s, 2, 64);
    float inv = 1.f / s;
    float4 o = make_float4(e0 * inv, e1 * inv, e2 * inv, e3 * inv);
    *(float4*)&y[(size_t)gnode * 16 + cg * 4] = o;
}

// ---------------- launch ----------------

extern "C" void kernel_launch(void* const* d_in, const int* in_sizes, int n_in,
                              void* d_out, int out_size, void* d_ws, size_t ws_size,
                              hipStream_t stream) {
    const float* x  = (const float*)d_in[0];
    const int*   ei = (const int*)d_in[1];
    const float* W1 = (const float*)d_in[2];
    const float* b1 = (const float*)d_in[3];
    const float* W2 = (const float*)d_in[4];
    const float* b2 = (const float*)d_in[5];
    float* y = (float*)d_out;

    char* p = (char*)d_ws;
    auto alloc = [&](size_t bytes) {
        char* q = p;
        p += (bytes + 255) & ~(size_t)255;
        return q;
    };
    int*   deg    = (int*)alloc((size_t)N_NODES * 4);
    float* dinv   = (float*)alloc((size_t)N_NODES * 4);
    int*   rowptr = (int*)alloc((size_t)(N_NODES + 1) * 4);
    int*   gcur   = (int*)alloc(256 * 4);
    int2*  csr_ew = (int2*)alloc((size_t)NBK * BKCAP * 8);
    __half* T     = (__half*)alloc((size_t)K1 * N_NODES * F * 2);
    __half* Wf    = (__half*)alloc((size_t)K1 * 2 * 4 * 64 * 8 * 2);

    // bucket buffer (196*9216*8B = 14.5 MB) aliases T: dead before k_cvt/k_prop write T.
    int2* bk = (int2*)T;

    hipMemsetAsync(gcur, 0, 256 * 4, stream);

    k_bucketA<<<(N_EDGES + EPB - 1) / EPB, 256, 0, stream>>>(ei, gcur, bk);
    k_degB<<<NBK, 256, 0, stream>>>(bk, gcur, deg, dinv, rowptr);
    k_fillB<<<NBK, 256, 0, stream>>>(bk, gcur, rowptr, dinv, csr_ew);
    k_prepW<<<16, 256, 0, stream>>>(W1, Wf);

    const size_t TSZ = (size_t)N_NODES * F;
    __half* Tk[K1];
    for (int k = 0; k < K1; k++) Tk[k] = T + (size_t)k * TSZ;

    k_cvt<<<(N_NODES * F / 4 + 255) / 256, 256, 0, stream>>>(x, Tk[0]);

    int npair = (N_NODES + 1) / 2;
    int prop_blocks = (npair + 3) / 4;
    k_prop<<<prop_blocks, 256, 0, stream>>>(rowptr, deg, csr_ew, Tk[0], Tk[0], Tk[1], 1.f, 0.f);
    for (int k = 2; k < K1; k++)
        k_prop<<<prop_blocks, 256, 0, stream>>>(rowptr, deg, csr_ew, Tk[k - 1], Tk[k - 2], Tk[k], 2.f, 1.f);

    int gemm_blocks = (N_NODES + 63) / 64;
    k_fused_mfma<<<gemm_blocks, 256, 0, stream>>>(T, Wf, b1, W2, b2, y);
}

// Round 15
// 307.835 us; speedup vs baseline: 1.9365x; 1.0544x over previous
//
#include <hip/hip_runtime.h>
#include <hip/hip_fp16.h>

#define N_NODES 100000
#define N_EDGES 1600000
#define F 64
#define NCLS 16
#define K1 8
#define BSH 9                  // bucket = row >> 9  (512 rows)
#define NBK 196                // ceil(100000 / 512)
#define BROWS 512
#define BKCAP 9216             // mean 8192 + ~11 sigma
#define EPB 4096               // bucketA edges per block
#define COLBITS 17             // N_NODES < 2^17

using f16x8 = __attribute__((ext_vector_type(8))) _Float16;
using f32x4 = __attribute__((ext_vector_type(4))) float;

// ---------------- pass A: bucket edges, 4 B packed (row_local<<17 | col) ----------------
__global__ __launch_bounds__(256) void k_bucketA(const int* __restrict__ ei,
                                                 int* __restrict__ gcur,
                                                 unsigned* __restrict__ bk) {
    __shared__ int cnt[4][256];
    __shared__ int wbase[4][256];
    int tid = threadIdx.x;
    int w = tid >> 6;
    for (int i = tid; i < 1024; i += 256) ((int*)cnt)[i] = 0;
    __syncthreads();
    unsigned pe[16];
    int packed[16];
    int e0 = blockIdx.x * EPB;
#pragma unroll
    for (int u = 0; u < 16; u++) {
        int e = e0 + u * 256 + tid;
        packed[u] = -1;
        if (e < N_EDGES) {
            int r = ei[e], c = ei[N_EDGES + e];
            if (r != c) {
                int b = r >> BSH;
                pe[u] = ((unsigned)(r & (BROWS - 1)) << COLBITS) | (unsigned)c;
                int rank = atomicAdd(&cnt[w][b], 1);
                packed[u] = (rank << 8) | b;
            }
        }
    }
    __syncthreads();
    {
        int c0 = cnt[0][tid], c1 = cnt[1][tid], c2 = cnt[2][tid], c3 = cnt[3][tid];
        int tot = c0 + c1 + c2 + c3;
        int g = tot ? atomicAdd(&gcur[tid], tot) : 0;
        wbase[0][tid] = g;
        wbase[1][tid] = g + c0;
        wbase[2][tid] = g + c0 + c1;
        wbase[3][tid] = g + c0 + c1 + c2;
    }
    __syncthreads();
#pragma unroll
    for (int u = 0; u < 16; u++) {
        if (packed[u] >= 0) {
            int b = packed[u] & 255;
            int rank = packed[u] >> 8;
            bk[(size_t)b * BKCAP + wbase[w][b] + rank] = pe[u];
        }
    }
}

// ---------------- pass B (fused): hist + scan + LDS counting-sort -> coalesced CSR ----------------
// one block per bucket. rowptr[gr] = b*BKCAP + local_excl; csr_col written streaming.
__global__ __launch_bounds__(256) void k_csrB(const unsigned* __restrict__ bk,
                                              const int* __restrict__ gcur,
                                              int* __restrict__ deg,
                                              float* __restrict__ dinv,
                                              int* __restrict__ rowptr,
                                              int* __restrict__ csr_col) {
    __shared__ int hist[BROWS];      // reused as rowoff after scan
    __shared__ int cur[BROWS];
    __shared__ int sd[256];
    __shared__ int sorted[BKCAP];
    int b = blockIdx.x;
    int tid = threadIdx.x;
    for (int i = tid; i < BROWS; i += 256) { hist[i] = 0; cur[i] = 0; }
    __syncthreads();
    int cnt = gcur[b];
    const unsigned* src = bk + (size_t)b * BKCAP;
    for (int i = tid; i < cnt; i += 256)
        atomicAdd(&hist[src[i] >> COLBITS], 1);
    __syncthreads();
    int v0 = hist[2 * tid], v1 = hist[2 * tid + 1];
    int s = v0 + v1;
    sd[tid] = s;
    __syncthreads();
    for (int d = 1; d < 256; d <<= 1) {
        int t = (tid >= d) ? sd[tid - d] : 0;
        __syncthreads();
        sd[tid] += t;
        __syncthreads();
    }
    int excl = sd[tid] - s;
    int rbase = b << BSH;
    int cbase = b * BKCAP;
    int gr0 = rbase + 2 * tid;
    int gr1 = gr0 + 1;
    if (gr0 < N_NODES) {
        deg[gr0] = v0;
        dinv[gr0] = v0 > 0 ? rsqrtf((float)v0) : 0.f;
        rowptr[gr0] = cbase + excl;
    }
    if (gr1 < N_NODES) {
        deg[gr1] = v1;
        dinv[gr1] = v1 > 0 ? rsqrtf((float)v1) : 0.f;
        rowptr[gr1] = cbase + excl + v0;
    }
    __syncthreads();
    hist[2 * tid] = excl;            // rowoff
    hist[2 * tid + 1] = excl + v0;
    __syncthreads();
    for (int i = tid; i < cnt; i += 256) {
        unsigned e = src[i];
        int rl = e >> COLBITS;
        int pos = hist[rl] + atomicAdd(&cur[rl], 1);
        sorted[pos] = (int)(e & ((1u << COLBITS) - 1));
    }
    __syncthreads();
    for (int i = tid; i < cnt; i += 256)
        csr_col[cbase + i] = sorted[i];
}

// ---------------- x fp32 -> fp16 ----------------
__global__ void k_cvt(const float* __restrict__ x, __half* __restrict__ t0) {
    int i = blockIdx.x * blockDim.x + threadIdx.x;
    int base = i * 4;
    if (base >= N_NODES * F) return;
    float4 v = *(const float4*)&x[base];
    __half2 a = __floats2half2_rn(v.x, v.y);
    __half2 b = __floats2half2_rn(v.z, v.w);
    *(__half2*)&t0[base] = a;
    *(__half2*)&t0[base + 2] = b;
}

// ---------------- W1 -> fp16 B-fragment layout ----------------
__global__ void k_prepW(const float* __restrict__ W1, __half* __restrict__ Wf) {
    int t = blockIdx.x * blockDim.x + threadIdx.x;
    if (t >= K1 * 2 * 4 * 64) return;
    int lane = t & 63;
    int cb = (t >> 6) & 3;
    int fg = (t >> 8) & 1;
    int kidx = t >> 9;
    int col = cb * 16 + (lane & 15);
    int kbase = fg * 32 + (lane >> 4) * 8;
    f16x8 v;
#pragma unroll
    for (int j = 0; j < 8; j++)
        v[j] = (_Float16)W1[kidx * 4096 + (kbase + j) * 64 + col];
    *(f16x8*)(Wf + (size_t)t * 8) = v;
}

// ---------------- propagation: col-only edges, weights factorized ----------------
// acc = sum dinv[c]*src[c]; res = -alpha*dinv[node]*acc - beta*prev.
// 2 nodes/wave, 8 lanes x 16 B per row, 4 rows per load instruction per node.
__global__ __launch_bounds__(256) void k_prop(const int* __restrict__ rowptr,
                                              const int* __restrict__ deg,
                                              const int* __restrict__ csr_col,
                                              const float* __restrict__ dinv,
                                              const __half* __restrict__ src,
                                              const __half* __restrict__ prev,
                                              __half* __restrict__ dst,
                                              float alpha, float beta) {
    int wpair = (int)((blockIdx.x * blockDim.x + threadIdx.x) >> 6);
    int lane = threadIdx.x & 63;
    int nA = wpair * 2;
    if (nA >= N_NODES) return;
    int h = lane >> 5;           // 0 = node A, 1 = node B
    int hl = lane & 31;
    int s3 = (lane >> 3) & 3;    // row slot within half
    int fb = (lane & 7) * 8;     // feature base (8 fp16 = 16 B)
    int node = nA + h;
    bool valid = node < N_NODES;
    int cb  = valid ? rowptr[node] : 0;
    int end = valid ? cb + deg[node] : 0;
    float dn = valid ? dinv[node] : 0.f;

    float acc[8] = {};

    while (true) {
        int n_own = end - cb;
        if (n_own > 32) n_own = 32;
        if (n_own < 0) n_own = 0;
        int n_oth = __shfl(n_own, lane ^ 32, 64);
        int nmax = n_own > n_oth ? n_own : n_oth;
        if (nmax == 0) break;
        int col = 0;
        float dv = 0.f;
        if (hl < n_own) {
            col = csr_col[cb + hl];
            dv = dinv[col];
        }
        for (int j = 0; j < nmax; j += 16) {
            int cc[4];
            float ww[4];
#pragma unroll
            for (int g = 0; g < 4; g++) {
                int sl = (h << 5) | (j + g * 4 + s3);
                cc[g] = __shfl(col, sl, 64);
                ww[g] = __shfl(dv, sl, 64);
            }
            uint4 raw[4];
#pragma unroll
            for (int g = 0; g < 4; g++)
                raw[g] = *(const uint4*)(src + (size_t)cc[g] * F + fb);
#pragma unroll
            for (int g = 0; g < 4; g++) {
                float2 f0 = __half22float2(*(__half2*)&raw[g].x);
                float2 f1 = __half22float2(*(__half2*)&raw[g].y);
                float2 f2 = __half22float2(*(__half2*)&raw[g].z);
                float2 f3 = __half22float2(*(__half2*)&raw[g].w);
                acc[0] = fmaf(ww[g], f0.x, acc[0]);
                acc[1] = fmaf(ww[g], f0.y, acc[1]);
                acc[2] = fmaf(ww[g], f1.x, acc[2]);
                acc[3] = fmaf(ww[g], f1.y, acc[3]);
                acc[4] = fmaf(ww[g], f2.x, acc[4]);
                acc[5] = fmaf(ww[g], f2.y, acc[5]);
                acc[6] = fmaf(ww[g], f3.x, acc[6]);
                acc[7] = fmaf(ww[g], f3.y, acc[7]);
            }
        }
        cb += n_own;
    }

    // fold slots: xor 8 / xor 16 stay within the 32-lane half, preserve lane&7
#pragma unroll
    for (int i = 0; i < 8; i++) {
        acc[i] += __shfl_xor(acc[i], 8, 64);
        acc[i] += __shfl_xor(acc[i], 16, 64);
    }

    if ((lane & 24) == 0 && valid) {
        float scale = -alpha * dn;
        float r[8];
#pragma unroll
        for (int i = 0; i < 8; i++) r[i] = scale * acc[i];
        if (beta != 0.f) {
            uint4 pv = *(const uint4*)(prev + (size_t)node * F + fb);
            float2 p0 = __half22float2(*(__half2*)&pv.x);
            float2 p1 = __half22float2(*(__half2*)&pv.y);
            float2 p2 = __half22float2(*(__half2*)&pv.z);
            float2 p3 = __half22float2(*(__half2*)&pv.w);
            r[0] -= beta * p0.x; r[1] -= beta * p0.y;
            r[2] -= beta * p1.x; r[3] -= beta * p1.y;
            r[4] -= beta * p2.x; r[5] -= beta * p2.y;
            r[6] -= beta * p3.x; r[7] -= beta * p3.y;
        }
        uint4 outv;
        *(__half2*)&outv.x = __floats2half2_rn(r[0], r[1]);
        *(__half2*)&outv.y = __floats2half2_rn(r[2], r[3]);
        *(__half2*)&outv.z = __floats2half2_rn(r[4], r[5]);
        *(__half2*)&outv.w = __floats2half2_rn(r[6], r[7]);
        *(uint4*)(dst + (size_t)node * F + fb) = outv;
    }
}

// ---------------- fused MFMA: y = softmax(relu(sum_k Tk@W1k + b1) @ W2 + b2) ----------------
__global__ __launch_bounds__(256) void k_fused_mfma(const __half* __restrict__ T,
                                                    const __half* __restrict__ Wf,
                                                    const float* __restrict__ b1,
                                                    const float* __restrict__ W2,
                                                    const float* __restrict__ b2,
                                                    float* __restrict__ y) {
    __shared__ float Ht[64][65];
    __shared__ float W2l[64 * 16];
    __shared__ float b2l[16];
    int tid = threadIdx.x;
    int lane = tid & 63;
    int w = tid >> 6;
    int ln15 = lane & 15;
    int lg = lane >> 4;
    int base = blockIdx.x * 64;

    for (int j = tid; j < 64 * 16; j += 256) W2l[j] = W2[j];
    if (tid < 16) b2l[tid] = b2[tid];

    int nd = base + (w << 4) + ln15;
    if (nd > N_NODES - 1) nd = N_NODES - 1;  // clamp: garbage rows, stores guarded

    f32x4 acc0 = {0.f, 0.f, 0.f, 0.f};
    f32x4 acc1 = {0.f, 0.f, 0.f, 0.f};
    f32x4 acc2 = {0.f, 0.f, 0.f, 0.f};
    f32x4 acc3 = {0.f, 0.f, 0.f, 0.f};

    for (int s = 0; s < 16; s++) {
        int kidx = s >> 1;
        int fg = s & 1;
        f16x8 a = *(const f16x8*)(T + ((size_t)kidx * N_NODES + nd) * F + fg * 32 + lg * 8);
        const __half* wb = Wf + ((size_t)((kidx * 2 + fg) * 4) * 64 + lane) * 8;
        f16x8 b0 = *(const f16x8*)(wb);
        f16x8 b1f = *(const f16x8*)(wb + 64 * 8);
        f16x8 b2f = *(const f16x8*)(wb + 128 * 8);
        f16x8 b3f = *(const f16x8*)(wb + 192 * 8);
        acc0 = __builtin_amdgcn_mfma_f32_16x16x32_f16(a, b0, acc0, 0, 0, 0);
        acc1 = __builtin_amdgcn_mfma_f32_16x16x32_f16(a, b1f, acc1, 0, 0, 0);
        acc2 = __builtin_amdgcn_mfma_f32_16x16x32_f16(a, b2f, acc2, 0, 0, 0);
        acc3 = __builtin_amdgcn_mfma_f32_16x16x32_f16(a, b3f, acc3, 0, 0, 0);
    }

    int hrow = (w << 4) + (lg << 2);
    {
        float bb0 = b1[0 * 16 + ln15];
        float bb1 = b1[1 * 16 + ln15];
        float bb2 = b1[2 * 16 + ln15];
        float bb3 = b1[3 * 16 + ln15];
#pragma unroll
        for (int r = 0; r < 4; r++) {
            float h0 = acc0[r] + bb0;
            float h1 = acc1[r] + bb1;
            float h2 = acc2[r] + bb2;
            float h3 = acc3[r] + bb3;
            Ht[hrow + r][0 * 16 + ln15] = h0 > 0.f ? h0 : 0.f;
            Ht[hrow + r][1 * 16 + ln15] = h1 > 0.f ? h1 : 0.f;
            Ht[hrow + r][2 * 16 + ln15] = h2 > 0.f ? h2 : 0.f;
            Ht[hrow + r][3 * 16 + ln15] = h3 > 0.f ? h3 : 0.f;
        }
    }
    __syncthreads();

    int node = tid >> 2;
    int cg = tid & 3;
    int gnode = base + node;
    if (gnode >= N_NODES) return;
    float l0 = b2l[cg * 4 + 0], l1 = b2l[cg * 4 + 1], l2 = b2l[cg * 4 + 2], l3 = b2l[cg * 4 + 3];
    for (int f = 0; f < 64; f++) {
        float h = Ht[node][f];
        l0 = fmaf(h, W2l[f * 16 + cg * 4 + 0], l0);
        l1 = fmaf(h, W2l[f * 16 + cg * 4 + 1], l1);
        l2 = fmaf(h, W2l[f * 16 + cg * 4 + 2], l2);
        l3 = fmaf(h, W2l[f * 16 + cg * 4 + 3], l3);
    }
    float m = fmaxf(fmaxf(l0, l1), fmaxf(l2, l3));
    m = fmaxf(m, __shfl_xor(m, 1, 64));
    m = fmaxf(m, __shfl_xor(m, 2, 64));
    float e0 = expf(l0 - m), e1 = expf(l1 - m), e2 = expf(l2 - m), e3 = expf(l3 - m);
    float s = e0 + e1 + e2 + e3;
    s += __shfl_xor(s, 1, 64);
    s += __shfl_xor(s, 2, 64);
    float inv = 1.f / s;
    float4 o = make_float4(e0 * inv, e1 * inv, e2 * inv, e3 * inv);
    *(float4*)&y[(size_t)gnode * 16 + cg * 4] = o;
}

// ---------------- launch ----------------

extern "C" void kernel_launch(void* const* d_in, const int* in_sizes, int n_in,
                              void* d_out, int out_size, void* d_ws, size_t ws_size,
                              hipStream_t stream) {
    const float* x  = (const float*)d_in[0];
    const int*   ei = (const int*)d_in[1];
    const float* W1 = (const float*)d_in[2];
    const float* b1 = (const float*)d_in[3];
    const float* W2 = (const float*)d_in[4];
    const float* b2 = (const float*)d_in[5];
    float* y = (float*)d_out;

    char* p = (char*)d_ws;
    auto alloc = [&](size_t bytes) {
        char* q = p;
        p += (bytes + 255) & ~(size_t)255;
        return q;
    };
    int*   deg     = (int*)alloc((size_t)N_NODES * 4);
    float* dinv    = (float*)alloc((size_t)N_NODES * 4);
    int*   rowptr  = (int*)alloc((size_t)N_NODES * 4);
    int*   gcur    = (int*)alloc(256 * 4);
    int*   csr_col = (int*)alloc((size_t)NBK * BKCAP * 4);
    __half* T      = (__half*)alloc((size_t)K1 * N_NODES * F * 2);
    __half* Wf     = (__half*)alloc((size_t)K1 * 2 * 4 * 64 * 8 * 2);

    // bucket buffer (196*9216*4B = 7.2 MB) aliases T: dead before k_cvt/k_prop write T.
    unsigned* bk = (unsigned*)T;

    hipMemsetAsync(gcur, 0, 256 * 4, stream);

    k_bucketA<<<(N_EDGES + EPB - 1) / EPB, 256, 0, stream>>>(ei, gcur, bk);
    k_csrB<<<NBK, 256, 0, stream>>>(bk, gcur, deg, dinv, rowptr, csr_col);
    k_prepW<<<16, 256, 0, stream>>>(W1, Wf);

    const size_t TSZ = (size_t)N_NODES * F;
    __half* Tk[K1];
    for (int k = 0; k < K1; k++) Tk[k] = T + (size_t)k * TSZ;

    k_cvt<<<(N_NODES * F / 4 + 255) / 256, 256, 0, stream>>>(x, Tk[0]);

    int npair = (N_NODES + 1) / 2;
    int prop_blocks = (npair + 3) / 4;
    k_prop<<<prop_blocks, 256, 0, stream>>>(rowptr, deg, csr_col, dinv, Tk[0], Tk[0], Tk[1], 1.f, 0.f);
    for (int k = 2; k < K1; k++)
        k_prop<<<prop_blocks, 256, 0, stream>>>(rowptr, deg, csr_col, dinv, Tk[k - 1], Tk[k - 2], Tk[k], 2.f, 1.f);

    int gemm_blocks = (N_NODES + 63) / 64;
    k_fused_mfma<<<gemm_blocks, 256, 0, stream>>>(T, Wf, b1, W2, b2, y);
}